// Round 10
// baseline (533.737 us; speedup 1.0000x reference)
//
#include <hip/hip_runtime.h>
#include <hip/hip_bf16.h>
#include <math.h>

typedef __hip_bfloat16 bf16;

#define SCALE_QK 0.17677669529663687f  /* 32^-0.5 */

__device__ __forceinline__ float b2f(bf16 v){ return __bfloat162float(v); }
__device__ __forceinline__ bf16  f2b(float v){ return __float2bfloat16(v); }
__device__ __forceinline__ short bfs(float x){ bf16 b = f2b(x); short s; __builtin_memcpy(&s, &b, 2); return s; }

struct __align__(16) bf16x8 { bf16 v[8]; };
struct __align__(8)  bf16x4 { bf16 v[4]; };

typedef __attribute__((ext_vector_type(8))) short sh8;
typedef __attribute__((ext_vector_type(4))) short sh4;
typedef __attribute__((ext_vector_type(4))) float f4;

#if defined(__has_builtin)
#if __has_builtin(__builtin_amdgcn_mfma_f32_16x16x16bf16_1k)
#define HAS_MFMA16 1
#else
#define HAS_MFMA16 0
#endif
#else
#define HAS_MFMA16 0
#endif

#if defined(__has_builtin)
#if __has_builtin(__builtin_amdgcn_exp2f)
#define EXP2(x) __builtin_amdgcn_exp2f(x)
#else
#define EXP2(x) exp2f(x)
#endif
#else
#define EXP2(x) exp2f(x)
#endif

// async global->LDS, 16B per lane. LDS dest must be wave-uniform base + lane*16 (linear).
__device__ __forceinline__ void gl16(const bf16* g, short* l) {
    __builtin_amdgcn_global_load_lds((const __attribute__((address_space(1))) void*)g,
                                     (__attribute__((address_space(3))) void*)l, 16, 0, 0);
}

// ---------------------------------------------------------------- 10 weight tensors f32 -> bf16, one launch
__global__ __launch_bounds__(256) void wcvt10_k(const float* s0, const float* s1, const float* s2, const float* s3,
                                                const float* s4, const float* s5, const float* s6, const float* s7,
                                                const float* s8, const float* s9,
                                                bf16* d0, bf16* d1, bf16* d2, bf16* d3, bf16* d4,
                                                bf16* d5, bf16* d6, bf16* d7, bf16* d8, bf16* d9) {
    const int sizes[10] = {196608, 65536, 262144, 262144, 196608, 65536, 262144, 262144, 131072, 131072};
    int which = blockIdx.y;
    const float* s; bf16* d;
    switch (which) {
        case 0: s = s0; d = d0; break;  case 1: s = s1; d = d1; break;
        case 2: s = s2; d = d2; break;  case 3: s = s3; d = d3; break;
        case 4: s = s4; d = d4; break;  case 5: s = s5; d = d5; break;
        case 6: s = s6; d = d6; break;  case 7: s = s7; d = d7; break;
        case 8: s = s8; d = d8; break;  default: s = s9; d = d9; break;
    }
    int i = blockIdx.x * 256 + threadIdx.x;
    if (i < sizes[which]) d[i] = f2b(s[i]);
}

// ---------------------------------------------------------------- pos-emb hidden build (both tables)
__global__ __launch_bounds__(256) void hidbuild_k(const float* __restrict__ w1a, const float* __restrict__ b1a,
                                                  const float* __restrict__ w1b, const float* __restrict__ b1b,
                                                  bf16* __restrict__ hidA, bf16* __restrict__ hidB) {
    const float* w1 = blockIdx.y ? w1b : w1a;
    const float* b1 = blockIdx.y ? b1b : b1a;
    bf16* hid       = blockIdx.y ? hidB : hidA;
    int t = blockIdx.x, tid = threadIdx.x;
    int i = t >> 6, j = (t >> 3) & 7, k = t & 7;
    float c0 = (i - 4) * 0.25f, c1 = (j - 4) * 0.25f, c2 = (k - 4) * 0.25f;
    #pragma unroll
    for (int rep = 0; rep < 2; rep++) {
        int jj = tid + rep * 256;
        float h = c0 * w1[jj*3+0] + c1 * w1[jj*3+1] + c2 * w1[jj*3+2] + b1[jj];
        hid[(size_t)t * 512 + jj] = f2b(fmaxf(h, 0.f));
    }
}

// ---------------------------------------------------------------- CPB table MLP (both tables, y picks)
// Writes PER-H REVERSED layout tab[h][3374 - t] with the sigmoid/exp2 fold applied:
// value = (16*sigmoid(mlp) - 24) * log2(e).  Reversal makes flash's 4-wide bias group
// {t0, t0-1, t0-2, t0-3} a CONTIGUOUS ascending run -> single dwordx4 load.
__device__ __forceinline__ float cpb_coord(int idx) {
    float v = (idx - 7) * (8.0f / 7.0f);
    return copysignf(log2f(fabsf(v) + 1.0f) * (1.0f / 3.0f), v);
}
__global__ __launch_bounds__(512) void cpbtab_k(const float* __restrict__ w1a, const float* __restrict__ b1a,
                                                const float* __restrict__ w2a, float* __restrict__ taba,
                                                const float* __restrict__ w1b, const float* __restrict__ b1b,
                                                const float* __restrict__ w2b, float* __restrict__ tabb) {
    const float* w1 = blockIdx.y ? w1b : w1a;
    const float* b1 = blockIdx.y ? b1b : b1a;
    const float* w2 = blockIdx.y ? w2b : w2a;
    float* tab      = blockIdx.y ? tabb : taba;
    int t = blockIdx.x, tid = threadIdx.x;
    __shared__ float hid[512];
    int i = t / 225, r = t - i * 225, j = r / 15, k = r - j * 15;
    float x0 = cpb_coord(i), x1 = cpb_coord(j), x2 = cpb_coord(k);
    float h = x0 * w1[tid*3+0] + x1 * w1[tid*3+1] + x2 * w1[tid*3+2] + b1[tid];
    hid[tid] = fmaxf(h, 0.f);
    __syncthreads();
    int h8 = tid >> 6, lane = tid & 63;
    float p = 0.f;
    for (int jj = lane; jj < 512; jj += 64) p += hid[jj] * w2[h8*512 + jj];
    for (int off = 32; off; off >>= 1) p += __shfl_down(p, off);
    if (lane == 0) {
        float bsig = 16.f / (1.f + __expf(-p));
        tab[h8 * 3375 + (3374 - t)] = (bsig - 24.0f) * 1.4426950408889634f;
    }
}

// ---------------------------------------------------------------- ct dewindow + hpe + LN (fused: writes ct0 f32 and LN'd bf16)
__global__ __launch_bounds__(256) void ct0ln_k(const float* __restrict__ ct_in,
                                               const float* __restrict__ hpe,
                                               const float* __restrict__ g,
                                               const float* __restrict__ b,
                                               float* __restrict__ ct0,
                                               bf16* __restrict__ lnout) {
    int u = blockIdx.x, c = threadIdx.x;
    int a = u >> 7, cc = (u >> 5) & 3, e = (u >> 4) & 1, bb = (u >> 2) & 3, d = (u >> 1) & 1, f = u & 1;
    int t = a * 128 + bb * 32 + cc * 8 + d * 4 + e * 2 + f;
    float x = ct_in[(size_t)t * 256 + c] + hpe[(size_t)u * 256 + c];
    ct0[(size_t)u * 256 + c] = x;
    float s = x, s2 = x * x;
    for (int off = 32; off; off >>= 1) { s += __shfl_down(s, off); s2 += __shfl_down(s2, off); }
    __shared__ float red[8];
    int wid = c >> 6, lane = c & 63;
    if (lane == 0) { red[wid] = s; red[wid + 4] = s2; }
    __syncthreads();
    if (c == 0) { red[0] = red[0] + red[1] + red[2] + red[3]; red[4] = red[4] + red[5] + red[6] + red[7]; }
    __syncthreads();
    float mean = red[0] * (1.f / 256.f);
    float var  = fmaxf(red[4] * (1.f / 256.f) - mean * mean, 0.f);
    float rstd = rsqrtf(var + 1e-5f);
    lnout[(size_t)u * 256 + c] = f2b((x - mean) * rstd * g[c] + b[c]);
}

// ---------------------------------------------------------------- LayerNorm f32 -> bf16 (legacy slab path)
__global__ __launch_bounds__(256) void ln_k(const float* __restrict__ in,
                                            const float* __restrict__ g,
                                            const float* __restrict__ b,
                                            bf16* __restrict__ out) {
    int row = blockIdx.x, c = threadIdx.x;
    float x = in[(size_t)row * 256 + c];
    float s = x, s2 = x * x;
    for (int off = 32; off; off >>= 1) { s += __shfl_down(s, off); s2 += __shfl_down(s2, off); }
    __shared__ float red[8];
    int wid = c >> 6, lane = c & 63;
    if (lane == 0) { red[wid] = s; red[wid + 4] = s2; }
    __syncthreads();
    if (c == 0) { red[0] = red[0] + red[1] + red[2] + red[3]; red[4] = red[4] + red[5] + red[6] + red[7]; }
    __syncthreads();
    float mean = red[0] * (1.f / 256.f);
    float var  = fmaxf(red[4] * (1.f / 256.f) - mean * mean, 0.f);
    float rstd = rsqrtf(var + 1e-5f);
    out[(size_t)row * 256 + c] = f2b((x - mean) * rstd * g[c] + b[c]);
}

// ---------------------------------------------------------------- MFMA GEMM, dbuf global_load_lds + COUNTED vmcnt (T4)
// MODE 0: bf16 store  MODE 1: bf16 GELU store  MODE 2: += f32 residual  MODE 3: f32 store (no bias)
template <int MODE>
__global__ __launch_bounds__(256) void gemm_k(const bf16* __restrict__ A,
                                              const bf16* __restrict__ W,
                                              const float* __restrict__ bias,
                                              int M, int N, int K,
                                              float* __restrict__ res,
                                              bf16* __restrict__ outb) {
    __shared__ short As[2][128 * 32];
    __shared__ short Ws[2][128 * 32];
    int m0 = blockIdx.y * 128, n0 = blockIdx.x * 128;
    int tid = threadIdx.x;
    int lane = tid & 63, wave = tid >> 6;
    int quad = lane >> 4, m16 = lane & 15;
    int wm = (wave & 1) * 64, wn = (wave >> 1) * 64;
    int arow = tid >> 2, acol = (tid & 3) * 8;

    const bf16* Ab = A + (size_t)(m0 + arow) * K + acol;
    const bf16* A2 = Ab + (size_t)64 * K;
    const bf16* Wb = W + (size_t)(n0 + arow) * K + acol;
    const bf16* W2 = Wb + (size_t)64 * K;

    f4 acc[4][4];
    #pragma unroll
    for (int i = 0; i < 4; i++)
        #pragma unroll
        for (int j = 0; j < 4; j++) acc[i][j] = (f4){0.f, 0.f, 0.f, 0.f};

    gl16(Ab, &As[0][tid * 8]);
    gl16(A2, &As[0][2048 + tid * 8]);
    gl16(Wb, &Ws[0][tid * 8]);
    gl16(W2, &Ws[0][2048 + tid * 8]);

    int cur = 0;
    for (int k0 = 0; k0 < K; k0 += 32) {
        int nxt = cur ^ 1;
        if (k0 + 32 < K) {
            gl16(Ab + k0 + 32, &As[nxt][tid * 8]);
            gl16(A2 + k0 + 32, &As[nxt][2048 + tid * 8]);
            gl16(Wb + k0 + 32, &Ws[nxt][tid * 8]);
            gl16(W2 + k0 + 32, &Ws[nxt][2048 + tid * 8]);
            asm volatile("s_waitcnt vmcnt(4)" ::: "memory");   // cur landed; nxt in flight
        } else {
            asm volatile("s_waitcnt vmcnt(0)" ::: "memory");   // last tile: drain
        }
        __builtin_amdgcn_s_barrier();
        sh8 af[4], bf[4];
        #pragma unroll
        for (int mi = 0; mi < 4; mi++)
            af[mi] = *reinterpret_cast<const sh8*>(&As[cur][(wm + mi * 16 + m16) * 32 + quad * 8]);
        #pragma unroll
        for (int ni = 0; ni < 4; ni++)
            bf[ni] = *reinterpret_cast<const sh8*>(&Ws[cur][(wn + ni * 16 + m16) * 32 + quad * 8]);
        #pragma unroll
        for (int mi = 0; mi < 4; mi++)
            #pragma unroll
            for (int ni = 0; ni < 4; ni++)
                acc[mi][ni] = __builtin_amdgcn_mfma_f32_16x16x32_bf16(af[mi], bf[ni], acc[mi][ni], 0, 0, 0);
        __builtin_amdgcn_s_barrier();
        cur = nxt;
    }
    (void)M;

    #pragma unroll
    for (int mi = 0; mi < 4; mi++) {
        #pragma unroll
        for (int r = 0; r < 4; r++) {
            int gm = m0 + wm + mi * 16 + quad * 4 + r;
            #pragma unroll
            for (int ni = 0; ni < 4; ni++) {
                int gn = n0 + wn + ni * 16 + m16;
                float v = acc[mi][ni][r];
                if constexpr (MODE != 3) v += bias[gn];
                if constexpr (MODE == 2)      res[(size_t)gm * N + gn] += v;
                else if constexpr (MODE == 3) res[(size_t)gm * N + gn] = v;
                else if constexpr (MODE == 1) outb[(size_t)gm * N + gn] = f2b(0.5f * v * (1.0f + erff(v * 0.70710678118654752f)));
                else                          outb[(size_t)gm * N + gn] = f2b(v);
            }
        }
    }
}

// ---------------------------------------------------------------- fused GEMM(N=256,K=256) + bias + residual(RMW xcat) + LayerNorm
__global__ __launch_bounds__(512) void gemmln_k(const bf16* __restrict__ A,
                                                const bf16* __restrict__ W,
                                                const float* __restrict__ bias,
                                                float* __restrict__ xcat,
                                                const float* __restrict__ g,
                                                const float* __restrict__ b,
                                                bf16* __restrict__ outb) {
    __shared__ short As[2][128 * 32];
    __shared__ short Ws[2][256 * 32];
    __shared__ float redS[128 * 4];
    __shared__ float redQ[128 * 4];
    __shared__ float stat[128 * 2];
    int m0 = blockIdx.x * 128;
    int tid = threadIdx.x;
    int lane = tid & 63, wave = tid >> 6;
    int quad = lane >> 4, m16 = lane & 15;
    int wm = (wave >> 2) * 64, wn = (wave & 3) * 64;
    int arow = tid >> 2, acol = (tid & 3) * 8;

    const bf16* Ab = A + (size_t)(m0 + arow) * 256 + acol;   // arow in 0..127
    const bf16* Wb = W + (size_t)arow * 256 + acol;
    const bf16* W2 = Wb + (size_t)128 * 256;

    f4 acc[4][4];
    #pragma unroll
    for (int i = 0; i < 4; i++)
        #pragma unroll
        for (int j = 0; j < 4; j++) acc[i][j] = (f4){0.f, 0.f, 0.f, 0.f};

    gl16(Ab, &As[0][tid * 8]);
    gl16(Wb, &Ws[0][tid * 8]);
    gl16(W2, &Ws[0][4096 + tid * 8]);

    int cur = 0;
    for (int k0 = 0; k0 < 256; k0 += 32) {
        int nxt = cur ^ 1;
        if (k0 + 32 < 256) {
            gl16(Ab + k0 + 32, &As[nxt][tid * 8]);
            gl16(Wb + k0 + 32, &Ws[nxt][tid * 8]);
            gl16(W2 + k0 + 32, &Ws[nxt][4096 + tid * 8]);
            asm volatile("s_waitcnt vmcnt(3)" ::: "memory");
        } else {
            asm volatile("s_waitcnt vmcnt(0)" ::: "memory");
        }
        __builtin_amdgcn_s_barrier();
        sh8 af[4], bf[4];
        #pragma unroll
        for (int mi = 0; mi < 4; mi++)
            af[mi] = *reinterpret_cast<const sh8*>(&As[cur][(wm + mi * 16 + m16) * 32 + quad * 8]);
        #pragma unroll
        for (int ni = 0; ni < 4; ni++)
            bf[ni] = *reinterpret_cast<const sh8*>(&Ws[cur][(wn + ni * 16 + m16) * 32 + quad * 8]);
        #pragma unroll
        for (int mi = 0; mi < 4; mi++)
            #pragma unroll
            for (int ni = 0; ni < 4; ni++)
                acc[mi][ni] = __builtin_amdgcn_mfma_f32_16x16x32_bf16(af[mi], bf[ni], acc[mi][ni], 0, 0, 0);
        __builtin_amdgcn_s_barrier();
        cur = nxt;
    }

    #pragma unroll
    for (int mi = 0; mi < 4; mi++) {
        #pragma unroll
        for (int r = 0; r < 4; r++) {
            int lr = wm + mi * 16 + quad * 4 + r;
            int gm = m0 + lr;
            float ps = 0.f, pq = 0.f;
            #pragma unroll
            for (int ni = 0; ni < 4; ni++) {
                int gc = wn + ni * 16 + m16;
                float v = acc[mi][ni][r] + bias[gc] + xcat[(size_t)gm * 256 + gc];
                acc[mi][ni][r] = v;
                ps += v; pq += v * v;
            }
            ps += __shfl_xor(ps, 1); pq += __shfl_xor(pq, 1);
            ps += __shfl_xor(ps, 2); pq += __shfl_xor(pq, 2);
            ps += __shfl_xor(ps, 4); pq += __shfl_xor(pq, 4);
            ps += __shfl_xor(ps, 8); pq += __shfl_xor(pq, 8);
            if (m16 == 0) { redS[lr * 4 + (wave & 3)] = ps; redQ[lr * 4 + (wave & 3)] = pq; }
        }
    }
    __syncthreads();
    if (tid < 128) {
        float s = redS[tid * 4] + redS[tid * 4 + 1] + redS[tid * 4 + 2] + redS[tid * 4 + 3];
        float q = redQ[tid * 4] + redQ[tid * 4 + 1] + redQ[tid * 4 + 2] + redQ[tid * 4 + 3];
        float mean = s * (1.f / 256.f);
        float var  = fmaxf(q * (1.f / 256.f) - mean * mean, 0.f);
        stat[tid * 2]     = mean;
        stat[tid * 2 + 1] = rsqrtf(var + 1e-5f);
    }
    __syncthreads();
    #pragma unroll
    for (int mi = 0; mi < 4; mi++) {
        #pragma unroll
        for (int r = 0; r < 4; r++) {
            int lr = wm + mi * 16 + quad * 4 + r;
            int gm = m0 + lr;
            float mean = stat[lr * 2], rstd = stat[lr * 2 + 1];
            #pragma unroll
            for (int ni = 0; ni < 4; ni++) {
                int gc = wn + ni * 16 + m16;
                float v = acc[mi][ni][r];
                xcat[(size_t)gm * 256 + gc] = v;
                outb[(size_t)gm * 256 + gc] = f2b((v - mean) * rstd * g[gc] + b[gc]);
            }
        }
    }
}

// ---------------------------------------------------------------- fused GEMM(N=256) + bias + residual(read xcat) + split write
__global__ __launch_bounds__(256) void gemmsplit_k(const bf16* __restrict__ A,
                                                   const bf16* __restrict__ W,
                                                   const float* __restrict__ bias,
                                                   int K,
                                                   const float* __restrict__ res,
                                                   float* __restrict__ out) {
    __shared__ short As[2][128 * 32];
    __shared__ short Ws[2][128 * 32];
    int m0 = blockIdx.y * 128, n0 = blockIdx.x * 128;
    int tid = threadIdx.x;
    int lane = tid & 63, wave = tid >> 6;
    int quad = lane >> 4, m16 = lane & 15;
    int wm = (wave & 1) * 64, wn = (wave >> 1) * 64;
    int arow = tid >> 2, acol = (tid & 3) * 8;

    const bf16* Ab = A + (size_t)(m0 + arow) * K + acol;
    const bf16* A2 = Ab + (size_t)64 * K;
    const bf16* Wb = W + (size_t)(n0 + arow) * K + acol;
    const bf16* W2 = Wb + (size_t)64 * K;

    f4 acc[4][4];
    #pragma unroll
    for (int i = 0; i < 4; i++)
        #pragma unroll
        for (int j = 0; j < 4; j++) acc[i][j] = (f4){0.f, 0.f, 0.f, 0.f};

    gl16(Ab, &As[0][tid * 8]);
    gl16(A2, &As[0][2048 + tid * 8]);
    gl16(Wb, &Ws[0][tid * 8]);
    gl16(W2, &Ws[0][2048 + tid * 8]);

    int cur = 0;
    for (int k0 = 0; k0 < K; k0 += 32) {
        int nxt = cur ^ 1;
        if (k0 + 32 < K) {
            gl16(Ab + k0 + 32, &As[nxt][tid * 8]);
            gl16(A2 + k0 + 32, &As[nxt][2048 + tid * 8]);
            gl16(Wb + k0 + 32, &Ws[nxt][tid * 8]);
            gl16(W2 + k0 + 32, &Ws[nxt][2048 + tid * 8]);
            asm volatile("s_waitcnt vmcnt(4)" ::: "memory");
        } else {
            asm volatile("s_waitcnt vmcnt(0)" ::: "memory");
        }
        __builtin_amdgcn_s_barrier();
        sh8 af[4], bf[4];
        #pragma unroll
        for (int mi = 0; mi < 4; mi++)
            af[mi] = *reinterpret_cast<const sh8*>(&As[cur][(wm + mi * 16 + m16) * 32 + quad * 8]);
        #pragma unroll
        for (int ni = 0; ni < 4; ni++)
            bf[ni] = *reinterpret_cast<const sh8*>(&Ws[cur][(wn + ni * 16 + m16) * 32 + quad * 8]);
        #pragma unroll
        for (int mi = 0; mi < 4; mi++)
            #pragma unroll
            for (int ni = 0; ni < 4; ni++)
                acc[mi][ni] = __builtin_amdgcn_mfma_f32_16x16x32_bf16(af[mi], bf[ni], acc[mi][ni], 0, 0, 0);
        __builtin_amdgcn_s_barrier();
        cur = nxt;
    }

    #pragma unroll
    for (int mi = 0; mi < 4; mi++) {
        #pragma unroll
        for (int r = 0; r < 4; r++) {
            int gm = m0 + wm + mi * 16 + quad * 4 + r;
            int w = gm / 520, p = gm - w * 520;
            size_t drow = (p >= 8) ? (size_t)(w * 512 + p - 8) : (size_t)(32768 + w * 8 + p);
            #pragma unroll
            for (int ni = 0; ni < 4; ni++) {
                int gn = n0 + wn + ni * 16 + m16;
                float v = acc[mi][ni][r] + bias[gn] + res[(size_t)gm * 256 + gn];
                out[drow * 256 + gn] = v;
            }
        }
    }
}

// ---------------------------------------------------------------- MFMA flash attention, fixed-max softmax (exp2 pre-folded)
// 512 threads (8 waves). qs in {0,1}: one full pair-unit per wave. qs==2: runt kt-split.
// R10: CPB table stored REVERSED (tabr[3374-t] = tab[t]) so the 4-wide bias group
// {t0, t0-1, t0-2, t0-3} = tabr[qrc+kidx .. qrc+kidx+3] -> ONE dwordx4 load (4B-aligned
// via memcpy) instead of 4 scalar loads + 4 address chains.
#define VSTR 548   /* shorts; step 18 mod 32 -> max 2-way (free), 8B-aligned */
#define SC2   0.25503575360579045f   /* SCALE_QK * log2(e) */
#define CNB  (-34.62468098133512f)   /* -24 * log2(e) */
#define NEGB (-1.0e30f)
__device__ __forceinline__ int cpb_kidx(int kl) {
    return (kl >> 6) * 225 + ((kl >> 3) & 7) * 15 + (kl & 7);
}
__device__ __forceinline__ int cpb_qconst(int ql) {
    return ((ql >> 6) + 7) * 225 + (((ql >> 3) & 7) + 7) * 15 + ((ql & 7) + 7);
}
// qrc = 3374 - cpb_qconst(q)
__device__ __forceinline__ f4 bias_tab(const float* __restrict__ tabh, bool vq, int qrc,
                                       int tg, int kidx, int N, int glob) {
    if (tg >= N) return (f4){NEGB, NEGB, NEGB, NEGB};
    if (vq && tg >= glob) {
        f4 v;
        __builtin_memcpy(&v, tabh + qrc + kidx, 16);
        return v;
    }
    return (f4){CNB, CNB, CNB, CNB};
}
__global__ __launch_bounds__(512) void flash_k(const bf16* __restrict__ qkv,
                                               const float* __restrict__ tab,
                                               bf16* __restrict__ out,
                                               int N, int glob) {
    int wh = blockIdx.x, w = wh >> 3, h = wh & 7;
    int qs = blockIdx.y;
    int tid = threadIdx.x;
    int lane = tid & 63, wave = tid >> 6;
    int quad = lane >> 4, qcol = lane & 15;
    const int NT32 = (N + 31) & ~31;
    const float* __restrict__ tabh = tab + h * 3375;

    __shared__ __align__(16) char smem[32 * VSTR * 2];   // Vt; runt reduce aliases it
    bf16* Vt = reinterpret_cast<bf16*>(smem);
#if !HAS_MFMA16
    __shared__ float Ps[8][16 * 17];
#endif

    for (int i = tid; i < NT32 * 4; i += 512) {
        int tok = i >> 2, seg = i & 3;
        if (tok < N) {
            const bf16* vp = qkv + ((size_t)(w * N + tok)) * 768 + 512 + h * 32 + seg * 8;
            bf16x8 vv = *reinterpret_cast<const bf16x8*>(vp);
            #pragma unroll
            for (int e = 0; e < 8; e++) Vt[(seg * 8 + e) * VSTR + tok] = vv.v[e];
        } else {
            bf16 z = f2b(0.f);
            #pragma unroll
            for (int e = 0; e < 8; e++) Vt[(seg * 8 + e) * VSTR + tok] = z;
        }
    }
    __syncthreads();

    const bf16* qbase = qkv + ((size_t)w * N) * 768 + h * 32;
    const bf16* kbase = qbase + 256;
    int nqt = (N + 15) >> 4, nkt = NT32 >> 5;
    int nfull = nqt >> 1;            // 16 for both call sites

    if (qs < 2) {
        int u = wave + 8 * qs;       // exactly one full pair unit per wave
        if (u < nfull) {
            int qA = u * 32 + qcol;  // always < N
            int qB = qA + 16;
            sh8 qfA = *reinterpret_cast<const sh8*>(qbase + (size_t)qA * 768 + quad * 8);
            sh8 qfB = *reinterpret_cast<const sh8*>(qbase + (size_t)qB * 768 + quad * 8);
            f4 O0A = {0.f,0.f,0.f,0.f}, O1A = {0.f,0.f,0.f,0.f};
            f4 O0B = {0.f,0.f,0.f,0.f}, O1B = {0.f,0.f,0.f,0.f};
            float lA = 0.f, lB = 0.f;
            bool vA = (qA >= glob);
            bool vB = (qB >= glob);
            int qrcA = vA ? (3374 - cpb_qconst(qA - glob)) : 0;
            int qrcB = vB ? (3374 - cpb_qconst(qB - glob)) : 0;

            // prefetch K frags for kt=0
            sh8 kf0, kf1;
            {
                int k0 = qcol, k1 = 16 + qcol;
                kf0 = *reinterpret_cast<const sh8*>(kbase + (size_t)((k0 < N) ? k0 : (N - 1)) * 768 + quad * 8);
                kf1 = *reinterpret_cast<const sh8*>(kbase + (size_t)((k1 < N) ? k1 : (N - 1)) * 768 + quad * 8);
            }

            for (int kt = 0; kt < nkt; kt++) {
                int bt = kt * 32;
                sh8 c0 = kf0, c1 = kf1;
                if (kt + 1 < nkt) {
                    int n0 = bt + 32 + qcol, n1 = bt + 48 + qcol;
                    kf0 = *reinterpret_cast<const sh8*>(kbase + (size_t)((n0 < N) ? n0 : (N - 1)) * 768 + quad * 8);
                    kf1 = *reinterpret_cast<const sh8*>(kbase + (size_t)((n1 < N) ? n1 : (N - 1)) * 768 + quad * 8);
                }
                f4 z = {0.f, 0.f, 0.f, 0.f};
                f4 s0A = __builtin_amdgcn_mfma_f32_16x16x32_bf16(c0, qfA, z, 0, 0, 0);
                f4 s1A = __builtin_amdgcn_mfma_f32_16x16x32_bf16(c1, qfA, z, 0, 0, 0);
                f4 s0B = __builtin_amdgcn_mfma_f32_16x16x32_bf16(c0, qfB, z, 0, 0, 0);
                f4 s1B = __builtin_amdgcn_mfma_f32_16x16x32_bf16(c1, qfB, z, 0, 0, 0);

                int tg0 = bt + quad * 4, tg1 = tg0 + 16;
                int kidx0 = cpb_kidx(tg0 - glob);
                int kidx1 = cpb_kidx(tg1 - glob);
                f4 bb0A = bias_tab(tabh, vA, qrcA, tg0, kidx0, N, glob);
                f4 bb1A = bias_tab(tabh, vA, qrcA, tg1, kidx1, N, glob);
                f4 bb0B = bias_tab(tabh, vB, qrcB, tg0, kidx0, N, glob);
                f4 bb1B = bias_tab(tabh, vB, qrcB, tg1, kidx1, N, glob);

                float pA[8], pB[8];
                #pragma unroll
                for (int r = 0; r < 4; r++) {
                    pA[r]     = EXP2(fmaf(s0A[r], SC2, bb0A[r]));
                    pA[4 + r] = EXP2(fmaf(s1A[r], SC2, bb1A[r]));
                    pB[r]     = EXP2(fmaf(s0B[r], SC2, bb0B[r]));
                    pB[4 + r] = EXP2(fmaf(s1B[r], SC2, bb1B[r]));
                }
                #pragma unroll
                for (int r = 0; r < 8; r++) { lA += pA[r]; lB += pB[r]; }

#if HAS_MFMA16
                sh4 v00 = *reinterpret_cast<const sh4*>(&Vt[qcol * VSTR + bt + quad * 4]);
                sh4 v10 = *reinterpret_cast<const sh4*>(&Vt[qcol * VSTR + bt + 16 + quad * 4]);
                sh4 v01 = *reinterpret_cast<const sh4*>(&Vt[(qcol + 16) * VSTR + bt + quad * 4]);
                sh4 v11 = *reinterpret_cast<const sh4*>(&Vt[(qcol + 16) * VSTR + bt + 16 + quad * 4]);
                sh4 pf0A, pf1A, pf0B, pf1B;
                #pragma unroll
                for (int r = 0; r < 4; r++) {
                    pf0A[r] = bfs(pA[r]); pf1A[r] = bfs(pA[4 + r]);
                    pf0B[r] = bfs(pB[r]); pf1B[r] = bfs(pB[4 + r]);
                }
                O0A = __builtin_amdgcn_mfma_f32_16x16x16bf16_1k(v00, pf0A, O0A, 0, 0, 0);
                O0A = __builtin_amdgcn_mfma_f32_16x16x16bf16_1k(v10, pf1A, O0A, 0, 0, 0);
                O1A = __builtin_amdgcn_mfma_f32_16x16x16bf16_1k(v01, pf0A, O1A, 0, 0, 0);
                O1A = __builtin_amdgcn_mfma_f32_16x16x16bf16_1k(v11, pf1A, O1A, 0, 0, 0);
                O0B = __builtin_amdgcn_mfma_f32_16x16x16bf16_1k(v00, pf0B, O0B, 0, 0, 0);
                O0B = __builtin_amdgcn_mfma_f32_16x16x16bf16_1k(v10, pf1B, O0B, 0, 0, 0);
                O1B = __builtin_amdgcn_mfma_f32_16x16x16bf16_1k(v01, pf0B, O1B, 0, 0, 0);
                O1B = __builtin_amdgcn_mfma_f32_16x16x16bf16_1k(v11, pf1B, O1B, 0, 0, 0);
#else
                for (int t = 0; t < 2; t++) {
                    const float* ph = t ? pB : pA;
                    for (int half = 0; half < 2; half++) {
                        #pragma unroll
                        for (int r = 0; r < 4; r++) Ps[wave][(quad * 4 + r) * 17 + qcol] = ph[half * 4 + r];
                        __builtin_amdgcn_wave_barrier();
                        sh8 pbig, va, vb;
                        #pragma unroll
                        for (int j = 0; j < 8; j++) {
                            int tl = quad * 8 + j;
                            float pv = (quad < 2) ? Ps[wave][tl * 17 + qcol] : 0.f;
                            pbig[j] = bfs(pv);
                            bf16 a0 = (quad < 2) ? Vt[qcol * VSTR + bt + half * 16 + tl] : f2b(0.f);
                            bf16 a1 = (quad < 2) ? Vt[(qcol + 16) * VSTR + bt + half * 16 + tl] : f2b(0.f);
                            short t0, t1;
                            __builtin_memcpy(&t0, &a0, 2); __builtin_memcpy(&t1, &a1, 2);
                            va[j] = t0; vb[j] = t1;
                        }
                        if (t == 0) {
                            O0A = __builtin_amdgcn_mfma_f32_16x16x32_bf16(va, pbig, O0A, 0, 0, 0);
                            O1A = __builtin_amdgcn_mfma_f32_16x16x32_bf16(vb, pbig, O1A, 0, 0, 0);
                        } else {
                            O0B = __builtin_amdgcn_mfma_f32_16x16x32_bf16(va, pbig, O0B, 0, 0, 0);
                            O1B = __builtin_amdgcn_mfma_f32_16x16x32_bf16(vb, pbig, O1B, 0, 0, 0);
                        }
                        __builtin_amdgcn_wave_barrier();
                    }
                }
#endif
            }

            lA += __shfl_xor(lA, 16); lA += __shfl_xor(lA, 32);
            lB += __shfl_xor(lB, 16); lB += __shfl_xor(lB, 32);
            float rlA = 1.f / lA, rlB = 1.f / lB;
            {
                bf16x4 o0, o1;
                #pragma unroll
                for (int r = 0; r < 4; r++) { o0.v[r] = f2b(O0A[r] * rlA); o1.v[r] = f2b(O1A[r] * rlA); }
                bf16* op = out + ((size_t)(w * N + qA)) * 256 + h * 32 + quad * 4;
                *reinterpret_cast<bf16x4*>(op)      = o0;
                *reinterpret_cast<bf16x4*>(op + 16) = o1;
            }
            {
                bf16x4 o0, o1;
                #pragma unroll
                for (int r = 0; r < 4; r++) { o0.v[r] = f2b(O0B[r] * rlB); o1.v[r] = f2b(O1B[r] * rlB); }
                bf16* op = out + ((size_t)(w * N + qB)) * 256 + h * 32 + quad * 4;
                *reinterpret_cast<bf16x4*>(op)      = o0;
                *reinterpret_cast<bf16x4*>(op + 16) = o1;
            }
        }
    } else {
        // ---- runt-only block: tile nqt-1, kt-split across the 8 waves ----
        int rt = nqt - 1;
        int qA = rt * 16 + qcol;            // may be >= N
        int qrA = (qA < N) ? qA : (N - 1);
        sh8 qfA = *reinterpret_cast<const sh8*>(qbase + (size_t)qrA * 768 + quad * 8);
        f4 O0 = {0.f,0.f,0.f,0.f}, O1 = {0.f,0.f,0.f,0.f};
        float l = 0.f;
        bool vA = (qA >= glob) && (qA < N);
        int qrcA = vA ? (3374 - cpb_qconst(qA - glob)) : 0;

        for (int kt = wave; kt < nkt; kt += 8) {
            int bt = kt * 32;
            int k0 = bt + qcol, k1 = bt + 16 + qcol;
            sh8 c0 = *reinterpret_cast<const sh8*>(kbase + (size_t)((k0 < N) ? k0 : (N - 1)) * 768 + quad * 8);
            sh8 c1 = *reinterpret_cast<const sh8*>(kbase + (size_t)((k1 < N) ? k1 : (N - 1)) * 768 + quad * 8);
            f4 z = {0.f, 0.f, 0.f, 0.f};
            f4 s0 = __builtin_amdgcn_mfma_f32_16x16x32_bf16(c0, qfA, z, 0, 0, 0);
            f4 s1 = __builtin_amdgcn_mfma_f32_16x16x32_bf16(c1, qfA, z, 0, 0, 0);

            int tg0 = bt + quad * 4, tg1 = tg0 + 16;
            int kidx0 = cpb_kidx(tg0 - glob);
            int kidx1 = cpb_kidx(tg1 - glob);
            f4 bb0 = bias_tab(tabh, vA, qrcA, tg0, kidx0, N, glob);
            f4 bb1 = bias_tab(tabh, vA, qrcA, tg1, kidx1, N, glob);

            float p[8];
            #pragma unroll
            for (int r = 0; r < 4; r++) {
                p[r]     = EXP2(fmaf(s0[r], SC2, bb0[r]));
                p[4 + r] = EXP2(fmaf(s1[r], SC2, bb1[r]));
            }
            #pragma unroll
            for (int r = 0; r < 8; r++) l += p[r];

#if HAS_MFMA16
            sh4 v00 = *reinterpret_cast<const sh4*>(&Vt[qcol * VSTR + bt + quad * 4]);
            sh4 v10 = *reinterpret_cast<const sh4*>(&Vt[qcol * VSTR + bt + 16 + quad * 4]);
            sh4 v01 = *reinterpret_cast<const sh4*>(&Vt[(qcol + 16) * VSTR + bt + quad * 4]);
            sh4 v11 = *reinterpret_cast<const sh4*>(&Vt[(qcol + 16) * VSTR + bt + 16 + quad * 4]);
            sh4 pf0, pf1;
            #pragma unroll
            for (int r = 0; r < 4; r++) { pf0[r] = bfs(p[r]); pf1[r] = bfs(p[4 + r]); }
            O0 = __builtin_amdgcn_mfma_f32_16x16x16bf16_1k(v00, pf0, O0, 0, 0, 0);
            O0 = __builtin_amdgcn_mfma_f32_16x16x16bf16_1k(v10, pf1, O0, 0, 0, 0);
            O1 = __builtin_amdgcn_mfma_f32_16x16x16bf16_1k(v01, pf0, O1, 0, 0, 0);
            O1 = __builtin_amdgcn_mfma_f32_16x16x16bf16_1k(v11, pf1, O1, 0, 0, 0);
#else
            for (int half = 0; half < 2; half++) {
                #pragma unroll
                for (int r = 0; r < 4; r++) Ps[wave][(quad * 4 + r) * 17 + qcol] = p[half * 4 + r];
                __builtin_amdgcn_wave_barrier();
                sh8 pbig, va, vb;
                #pragma unroll
                for (int j = 0; j < 8; j++) {
                    int tl = quad * 8 + j;
                    float pv = (quad < 2) ? Ps[wave][tl * 17 + qcol] : 0.f;
                    pbig[j] = bfs(pv);
                    bf16 a0 = (quad < 2) ? Vt[qcol * VSTR + bt + half * 16 + tl] : f2b(0.f);
                    bf16 a1 = (quad < 2) ? Vt[(qcol + 16) * VSTR + bt + half * 16 + tl] : f2b(0.f);
                    short t0, t1;
                    __builtin_memcpy(&t0, &a0, 2); __builtin_memcpy(&t1, &a1, 2);
                    va[j] = t0; vb[j] = t1;
                }
                O0 = __builtin_amdgcn_mfma_f32_16x16x32_bf16(va, pbig, O0, 0, 0, 0);
                O1 = __builtin_amdgcn_mfma_f32_16x16x32_bf16(vb, pbig, O1, 0, 0, 0);
                __builtin_amdgcn_wave_barrier();
            }
#endif
        }

        // all Vt reads done -> safe to alias the reduce buffer over Vt
        __syncthreads();
        float (*red)[64][9] = reinterpret_cast<float (*)[64][9]>(smem);
        #pragma unroll
        for (int r = 0; r < 4; r++) { red[wave][lane][r] = O0[r]; red[wave][lane][4 + r] = O1[r]; }
        red[wave][lane][8] = l;
        __syncthreads();

        if (wave == 0) {
            f4 O0s = {0.f,0.f,0.f,0.f}, O1s = {0.f,0.f,0.f,0.f};
            float ls = 0.f;
            for (int v = 0; v < 8; v++) {
                #pragma unroll
                for (int r = 0; r < 4; r++) { O0s[r] += red[v][lane][r]; O1s[r] += red[v][lane][4 + r]; }
                ls += red[v][lane][8];
            }
            ls += __shfl_xor(ls, 16); ls += __shfl_xor(ls, 32);
            float rl = 1.f / ls;
            if (qA < N) {
                bf16x4 o0, o1;
                #pragma unroll
                for (int r = 0; r < 4; r++) { o0.v[r] = f2b(O0s[r] * rl); o1.v[r] = f2b(O1s[r] * rl); }
                bf16* op = out + ((size_t)(w * N + qA)) * 256 + h * 32 + quad * 4;
                *reinterpret_cast<bf16x4*>(op)      = o0;
                *reinterpret_cast<bf16x4*>(op + 16) = o1;
            }
        }
    }
}

// ---------------------------------------------------------------- xcat build + LN1 fused: writes xcat f32 and xln bf16
__global__ __launch_bounds__(256) void xcatln_k(const float* __restrict__ x_in,
                                                const float* __restrict__ pe,
                                                const float* __restrict__ ct2,
                                                const float* __restrict__ g,
                                                const float* __restrict__ b,
                                                float* __restrict__ xcat,
                                                bf16* __restrict__ xln) {
    int row = blockIdx.x, w = row / 520, p = row - w * 520, c = threadIdx.x;
    float v;
    if (p < 8) {
        int P = w >> 4, Q = (w >> 2) & 3, R = w & 3;
        int S = p >> 2, T = (p >> 1) & 1, U = p & 1;
        int t = P * 128 + S * 64 + Q * 16 + T * 8 + R * 2 + U;
        v = ct2[(size_t)t * 256 + c];
    } else {
        int t = p - 8;
        v = x_in[((size_t)w * 512 + t) * 256 + c] + pe[(size_t)t * 256 + c];
    }
    xcat[(size_t)row * 256 + c] = v;
    float s = v, s2 = v * v;
    for (int off = 32; off; off >>= 1) { s += __shfl_down(s, off); s2 += __shfl_down(s2, off); }
    __shared__ float red[8];
    int wid = c >> 6, lane = c & 63;
    if (lane == 0) { red[wid] = s; red[wid + 4] = s2; }
    __syncthreads();
    if (c == 0) { red[0] = red[0] + red[1] + red[2] + red[3]; red[4] = red[4] + red[5] + red[6] + red[7]; }
    __syncthreads();
    float mean = red[0] * (1.f / 256.f);
    float var  = fmaxf(red[4] * (1.f / 256.f) - mean * mean, 0.f);
    float rstd = rsqrtf(var + 1e-5f);
    xln[(size_t)row * 256 + c] = f2b((v - mean) * rstd * g[c] + b[c]);
}

// ---------------------------------------------------------------- xcat build (legacy slab path)
__global__ __launch_bounds__(256) void xcatbuild_k(const float* __restrict__ x_in,
                                                   const float* __restrict__ pe,
                                                   const float* __restrict__ ct2,
                                                   float* __restrict__ xcat) {
    int row = blockIdx.x, w = row / 520, p = row - w * 520, c = threadIdx.x;
    float v;
    if (p < 8) {
        int P = w >> 4, Q = (w >> 2) & 3, R = w & 3;
        int S = p >> 2, T = (p >> 1) & 1, U = p & 1;
        int t = P * 128 + S * 64 + Q * 16 + T * 8 + R * 2 + U;
        v = ct2[(size_t)t * 256 + c];
    } else {
        int t = p - 8;
        v = x_in[((size_t)w * 512 + t) * 256 + c] + pe[(size_t)t * 256 + c];
    }
    xcat[(size_t)row * 256 + c] = v;
}

// ---------------------------------------------------------------- output split (legacy slab path)
__global__ __launch_bounds__(256) void outbuild_k(const float* __restrict__ xcat,
                                                  float* __restrict__ out) {
    int row = blockIdx.x, w = row / 520, p = row - w * 520, c = threadIdx.x;
    float v = xcat[(size_t)row * 256 + c];
    if (p >= 8) out[((size_t)(w * 512) + (p - 8)) * 256 + c] = v;
    else        out[(size_t)8388608 + ((size_t)(w * 8) + p) * 256 + c] = v;
}

// ----------------------------------------------------------------
extern "C" void kernel_launch(void* const* d_in, const int* in_sizes, int n_in,
                              void* d_out, int out_size, void* d_ws, size_t ws_size,
                              hipStream_t stream) {
    const float* x          = (const float*)d_in[0];
    const float* ct         = (const float*)d_in[1];
    const float* pe_w1      = (const float*)d_in[2];
    const float* pe_b1      = (const float*)d_in[3];
    const float* pe_w2      = (const float*)d_in[4];
    const float* hpe_w1     = (const float*)d_in[5];
    const float* hpe_b1     = (const float*)d_in[6];
    const float* hpe_w2     = (const float*)d_in[7];
    const float* hat_n1_g   = (const float*)d_in[8];
    const float* hat_n1_b   = (const float*)d_in[9];
    const float* hat_qkv_w  = (const float*)d_in[10];
    const float* hat_qkv_b  = (const float*)d_in[11];
    const float* hat_proj_w = (const float*)d_in[12];
    const float* hat_proj_b = (const float*)d_in[13];
    const float* hat_cpb_w1 = (const float*)d_in[14];
    const float* hat_cpb_b1 = (const float*)d_in[15];
    const float* hat_cpb_w2 = (const float*)d_in[16];
    const float* hat_n2_g   = (const float*)d_in[17];
    const float* hat_n2_b   = (const float*)d_in[18];
    const float* hat_fc1_w  = (const float*)d_in[19];
    const float* hat_fc1_b  = (const float*)d_in[20];
    const float* hat_fc2_w  = (const float*)d_in[21];
    const float* hat_fc2_b  = (const float*)d_in[22];
    const float* n1_g       = (const float*)d_in[23];
    const float* n1_b       = (const float*)d_in[24];
    const float* qkv_w      = (const float*)d_in[25];
    const float* qkv_b      = (const float*)d_in[26];
    const float* proj_w     = (const float*)d_in[27];
    const float* proj_b     = (const float*)d_in[28];
    const float* cpb_w1     = (const float*)d_in[29];
    const float* cpb_b1     = (const float*)d_in[30];
    const float* cpb_w2     = (const float*)d_in[31];
    const float* n2_g       = (const float*)d_in[32];
    const float* n2_b       = (const float*)d_in[33];
    const float* fc1_w      = (const float*)d_in[34];
    const float* fc1_b      = (const float*)d_in[35];
    const float* fc2_w      = (const float*)d_in[36];
    const float* fc2_b      = (const float*)d_in[37];
    (void)in_sizes; (void)n_in; (void)out_size;

    char* base = (char*)d_ws;
    size_t off = 0;
    auto alloc = [&](size_t bytes) -> void* {
        void* p = base + off;
        off += (bytes + 255) & ~(size_t)255;
        return p;
    };
    // persistent
    float* pe        = (float*)alloc(512 * 256 * 4);
    float* hpe       = (float*)alloc(512 * 256 * 4);
    float* tab_hat   = (float*)alloc(8 * 3375 * 4);   // per-h folded+reversed CPB tables
    float* tab2      = (float*)alloc(8 * 3375 * 4);
    float* ct0       = (float*)alloc(512 * 256 * 4);
    bf16* wb_hqkv  = (bf16*)alloc(768 * 256 * 2);
    bf16* wb_hproj = (bf16*)alloc(256 * 256 * 2);
    bf16* wb_hfc1  = (bf16*)alloc(1024 * 256 * 2);
    bf16* wb_hfc2  = (bf16*)alloc(256 * 1024 * 2);
    bf16* wb_qkv   = (bf16*)alloc(768 * 256 * 2);
    bf16* wb_proj  = (bf16*)alloc(256 * 256 * 2);
    bf16* wb_fc1   = (bf16*)alloc(1024 * 256 * 2);
    bf16* wb_fc2   = (bf16*)alloc(256 * 1024 * 2);
    bf16* wb_pew2  = (bf16*)alloc(256 * 512 * 2);
    bf16* wb_hpew2 = (bf16*)alloc(256 * 512 * 2);
    size_t zstart = off;
    // phase-1 temporaries
    bf16*  hidA      = (bf16*)alloc(512 * 512 * 2);
    bf16*  hidB      = (bf16*)alloc(512 * 512 * 2);
    off = zstart;
    // hat-phase temporaries — dead before xcat is written
    bf16*  hct_ln    = (bf16*)alloc(512 * 256 * 2);
    bf16*  hqkv      = (bf16*)alloc(512 * 768 * 2);
    bf16*  hat_attn  = (bf16*)alloc(512 * 256 * 2);
    bf16*  hat_hid   = (bf16*)alloc(512 * 1024 * 2);
    // main-phase buffers overlay hat temporaries; slab count gated on ws_size
    off = zstart;
    float* xcat      = (float*)alloc((size_t)64 * 520 * 256 * 4);   // 34.1 MB
    const int S     = (ws_size >= (size_t)150 * 1024 * 1024) ? 1 : 4;
    const int rows  = 33280 / S;
    const int wins  = 64 / S;
    bf16*  xln_b     = (bf16*)alloc((size_t)rows * 256 * 2);
    char*  region_qa = (char*)alloc((size_t)rows * 1024 * 2);       // qkv+attn, or MLP hidden
    bf16*  qkv_b_    = (bf16*)region_qa;
    bf16*  attn_b    = (bf16*)(region_qa + (size_t)rows * 768 * 2);
    bf16*  hidden    = (bf16*)region_qa;

    // weight conversion (one launch)
    wcvt10_k<<<dim3(1024, 10), 256, 0, stream>>>(hat_qkv_w, hat_proj_w, hat_fc1_w, hat_fc2_w,
                                                 qkv_w, proj_w, fc1_w, fc2_w, pe_w2, hpe_w2,
                                                 wb_hqkv, wb_hproj, wb_hfc1, wb_hfc2,
                                                 wb_qkv, wb_proj, wb_fc1, wb_fc2, wb_pew2, wb_hpew2);

    // pos-emb: hidden build + MFMA gemm (M=512,N=256,K=512, f32 store)
    hidbuild_k<<<dim3(512, 2), 256, 0, stream>>>(pe_w1, pe_b1, hpe_w1, hpe_b1, hidA, hidB);
    gemm_k<3><<<dim3(2, 4), 256, 0, stream>>>(hidA, wb_pew2,  nullptr, 512, 256, 512, pe,  nullptr);
    gemm_k<3><<<dim3(2, 4), 256, 0, stream>>>(hidB, wb_hpew2, nullptr, 512, 256, 512, hpe, nullptr);

    // CPB tables (per-h folded + reversed; no bias materialization needed)
    cpbtab_k<<<dim3(3375, 2), 512, 0, stream>>>(hat_cpb_w1, hat_cpb_b1, hat_cpb_w2, tab_hat,
                                                cpb_w1, cpb_b1, cpb_w2, tab2);

    // hat branch (512 tokens, 1 window, glob=0; nqt=32 -> no runt, qs in {0,1})
    ct0ln_k<<<512, 256, 0, stream>>>(ct, hpe, hat_n1_g, hat_n1_b, ct0, hct_ln);
    gemm_k<0><<<dim3(6, 4), 256, 0, stream>>>(hct_ln, wb_hqkv, hat_qkv_b, 512, 768, 256, nullptr, hqkv);
    flash_k<<<dim3(8, 2), 512, 0, stream>>>(hqkv, tab_hat, hat_attn, 512, 0);
    gemmln_k<<<4, 512, 0, stream>>>(hat_attn, wb_hproj, hat_proj_b, ct0, hat_n2_g, hat_n2_b, hct_ln);
    gemm_k<1><<<dim3(8, 4), 256, 0, stream>>>(hct_ln, wb_hfc1, hat_fc1_b, 512, 1024, 256, nullptr, hat_hid);
    gemm_k<2><<<dim3(2, 4), 256, 0, stream>>>(hat_hid, wb_hfc2, hat_fc2_b, 512, 256, 1024, ct0, nullptr);

    if (S == 1) {
        // fused pipeline: concat+LN1, qkv, flash, proj+res+LN2, fc1(GELU), fc2+res+split
        xcatln_k<<<33280, 256, 0, stream>>>(x, pe, ct0, n1_g, n1_b, xcat, xln_b);
        gemm_k<0><<<dim3(6, 260), 256, 0, stream>>>(xln_b, wb_qkv, qkv_b, 33280, 768, 256, nullptr, qkv_b_);
        flash_k<<<dim3(512, 3), 512, 0, stream>>>(qkv_b_, tab2, attn_b, 520, 8);
        gemmln_k<<<260, 512, 0, stream>>>(attn_b, wb_proj, proj_b, xcat, n2_g, n2_b, xln_b);
        gemm_k<1><<<dim3(8, 260), 256, 0, stream>>>(xln_b, wb_fc1, fc1_b, 33280, 1024, 256, nullptr, hidden);
        gemmsplit_k<<<dim3(2, 260), 256, 0, stream>>>(hidden, wb_fc2, fc2_b, 1024, xcat, (float*)d_out);
    } else {
        // legacy slab path
        xcatbuild_k<<<33280, 256, 0, stream>>>(x, pe, ct0, xcat);
        for (int s = 0; s < S; s++) {
            float* xc = xcat + (size_t)s * rows * 256;
            ln_k<<<rows, 256, 0, stream>>>(xc, n1_g, n1_b, xln_b);
            gemm_k<0><<<dim3(6, rows / 128), 256, 0, stream>>>(xln_b, wb_qkv, qkv_b, rows, 768, 256, nullptr, qkv_b_);
            flash_k<<<dim3(wins * 8, 3), 512, 0, stream>>>(qkv_b_, tab2, attn_b, 520, 8);
            gemm_k<2><<<dim3(2, rows / 128), 256, 0, stream>>>(attn_b, wb_proj, proj_b, rows, 256, 256, xc, nullptr);
        }
        for (int s = 0; s < S; s++) {
            float* xc = xcat + (size_t)s * rows * 256;
            ln_k<<<rows, 256, 0, stream>>>(xc, n2_g, n2_b, xln_b);
            gemm_k<1><<<dim3(8, rows / 128), 256, 0, stream>>>(xln_b, wb_fc1, fc1_b, rows, 1024, 256, nullptr, hidden);
            gemm_k<2><<<dim3(2, rows / 128), 256, 0, stream>>>(hidden, wb_fc2, fc2_b, rows, 256, 1024, xc, nullptr);
        }
        outbuild_k<<<33280, 256, 0, stream>>>(xcat, (float*)d_out);
    }
}

// Round 11
// 529.639 us; speedup vs baseline: 1.0077x; 1.0077x over previous
//
#include <hip/hip_runtime.h>
#include <hip/hip_bf16.h>
#include <math.h>

typedef __hip_bfloat16 bf16;

#define SCALE_QK 0.17677669529663687f  /* 32^-0.5 */

__device__ __forceinline__ float b2f(bf16 v){ return __bfloat162float(v); }
__device__ __forceinline__ bf16  f2b(float v){ return __float2bfloat16(v); }
__device__ __forceinline__ short bfs(float x){ bf16 b = f2b(x); short s; __builtin_memcpy(&s, &b, 2); return s; }

struct __align__(16) bf16x8 { bf16 v[8]; };
struct __align__(8)  bf16x4 { bf16 v[4]; };

typedef __attribute__((ext_vector_type(8))) short sh8;
typedef __attribute__((ext_vector_type(4))) short sh4;
typedef __attribute__((ext_vector_type(4))) float f4;

#if defined(__has_builtin)
#if __has_builtin(__builtin_amdgcn_mfma_f32_16x16x16bf16_1k)
#define HAS_MFMA16 1
#else
#define HAS_MFMA16 0
#endif
#else
#define HAS_MFMA16 0
#endif

#if defined(__has_builtin)
#if __has_builtin(__builtin_amdgcn_exp2f)
#define EXP2(x) __builtin_amdgcn_exp2f(x)
#else
#define EXP2(x) exp2f(x)
#endif
#else
#define EXP2(x) exp2f(x)
#endif

// async global->LDS, 16B per lane. LDS dest must be wave-uniform base + lane*16 (linear).
__device__ __forceinline__ void gl16(const bf16* g, short* l) {
    __builtin_amdgcn_global_load_lds((const __attribute__((address_space(1))) void*)g,
                                     (__attribute__((address_space(3))) void*)l, 16, 0, 0);
}

// ---------------------------------------------------------------- 10 weight tensors f32 -> bf16, one launch
__global__ __launch_bounds__(256) void wcvt10_k(const float* s0, const float* s1, const float* s2, const float* s3,
                                                const float* s4, const float* s5, const float* s6, const float* s7,
                                                const float* s8, const float* s9,
                                                bf16* d0, bf16* d1, bf16* d2, bf16* d3, bf16* d4,
                                                bf16* d5, bf16* d6, bf16* d7, bf16* d8, bf16* d9) {
    const int sizes[10] = {196608, 65536, 262144, 262144, 196608, 65536, 262144, 262144, 131072, 131072};
    int which = blockIdx.y;
    const float* s; bf16* d;
    switch (which) {
        case 0: s = s0; d = d0; break;  case 1: s = s1; d = d1; break;
        case 2: s = s2; d = d2; break;  case 3: s = s3; d = d3; break;
        case 4: s = s4; d = d4; break;  case 5: s = s5; d = d5; break;
        case 6: s = s6; d = d6; break;  case 7: s = s7; d = d7; break;
        case 8: s = s8; d = d8; break;  default: s = s9; d = d9; break;
    }
    int i = blockIdx.x * 256 + threadIdx.x;
    if (i < sizes[which]) d[i] = f2b(s[i]);
}

// ---------------------------------------------------------------- pos-emb hidden build (both tables)
__global__ __launch_bounds__(256) void hidbuild_k(const float* __restrict__ w1a, const float* __restrict__ b1a,
                                                  const float* __restrict__ w1b, const float* __restrict__ b1b,
                                                  bf16* __restrict__ hidA, bf16* __restrict__ hidB) {
    const float* w1 = blockIdx.y ? w1b : w1a;
    const float* b1 = blockIdx.y ? b1b : b1a;
    bf16* hid       = blockIdx.y ? hidB : hidA;
    int t = blockIdx.x, tid = threadIdx.x;
    int i = t >> 6, j = (t >> 3) & 7, k = t & 7;
    float c0 = (i - 4) * 0.25f, c1 = (j - 4) * 0.25f, c2 = (k - 4) * 0.25f;
    #pragma unroll
    for (int rep = 0; rep < 2; rep++) {
        int jj = tid + rep * 256;
        float h = c0 * w1[jj*3+0] + c1 * w1[jj*3+1] + c2 * w1[jj*3+2] + b1[jj];
        hid[(size_t)t * 512 + jj] = f2b(fmaxf(h, 0.f));
    }
}

// ---------------------------------------------------------------- CPB table MLP (both tables, y picks)
// Writes PER-H REVERSED layout tab[h][3374 - t] with the sigmoid/exp2 fold applied:
// value = (16*sigmoid(mlp) - 24) * log2(e).
__device__ __forceinline__ float cpb_coord(int idx) {
    float v = (idx - 7) * (8.0f / 7.0f);
    return copysignf(log2f(fabsf(v) + 1.0f) * (1.0f / 3.0f), v);
}
__global__ __launch_bounds__(512) void cpbtab_k(const float* __restrict__ w1a, const float* __restrict__ b1a,
                                                const float* __restrict__ w2a, float* __restrict__ taba,
                                                const float* __restrict__ w1b, const float* __restrict__ b1b,
                                                const float* __restrict__ w2b, float* __restrict__ tabb) {
    const float* w1 = blockIdx.y ? w1b : w1a;
    const float* b1 = blockIdx.y ? b1b : b1a;
    const float* w2 = blockIdx.y ? w2b : w2a;
    float* tab      = blockIdx.y ? tabb : taba;
    int t = blockIdx.x, tid = threadIdx.x;
    __shared__ float hid[512];
    int i = t / 225, r = t - i * 225, j = r / 15, k = r - j * 15;
    float x0 = cpb_coord(i), x1 = cpb_coord(j), x2 = cpb_coord(k);
    float h = x0 * w1[tid*3+0] + x1 * w1[tid*3+1] + x2 * w1[tid*3+2] + b1[tid];
    hid[tid] = fmaxf(h, 0.f);
    __syncthreads();
    int h8 = tid >> 6, lane = tid & 63;
    float p = 0.f;
    for (int jj = lane; jj < 512; jj += 64) p += hid[jj] * w2[h8*512 + jj];
    for (int off = 32; off; off >>= 1) p += __shfl_down(p, off);
    if (lane == 0) {
        float bsig = 16.f / (1.f + __expf(-p));
        tab[h8 * 3375 + (3374 - t)] = (bsig - 24.0f) * 1.4426950408889634f;
    }
}

// ---------------------------------------------------------------- ct dewindow + hpe + LN (fused: writes ct0 f32 and LN'd bf16)
__global__ __launch_bounds__(256) void ct0ln_k(const float* __restrict__ ct_in,
                                               const float* __restrict__ hpe,
                                               const float* __restrict__ g,
                                               const float* __restrict__ b,
                                               float* __restrict__ ct0,
                                               bf16* __restrict__ lnout) {
    int u = blockIdx.x, c = threadIdx.x;
    int a = u >> 7, cc = (u >> 5) & 3, e = (u >> 4) & 1, bb = (u >> 2) & 3, d = (u >> 1) & 1, f = u & 1;
    int t = a * 128 + bb * 32 + cc * 8 + d * 4 + e * 2 + f;
    float x = ct_in[(size_t)t * 256 + c] + hpe[(size_t)u * 256 + c];
    ct0[(size_t)u * 256 + c] = x;
    float s = x, s2 = x * x;
    for (int off = 32; off; off >>= 1) { s += __shfl_down(s, off); s2 += __shfl_down(s2, off); }
    __shared__ float red[8];
    int wid = c >> 6, lane = c & 63;
    if (lane == 0) { red[wid] = s; red[wid + 4] = s2; }
    __syncthreads();
    if (c == 0) { red[0] = red[0] + red[1] + red[2] + red[3]; red[4] = red[4] + red[5] + red[6] + red[7]; }
    __syncthreads();
    float mean = red[0] * (1.f / 256.f);
    float var  = fmaxf(red[4] * (1.f / 256.f) - mean * mean, 0.f);
    float rstd = rsqrtf(var + 1e-5f);
    lnout[(size_t)u * 256 + c] = f2b((x - mean) * rstd * g[c] + b[c]);
}

// ---------------------------------------------------------------- LayerNorm f32 -> bf16 (legacy slab path)
__global__ __launch_bounds__(256) void ln_k(const float* __restrict__ in,
                                            const float* __restrict__ g,
                                            const float* __restrict__ b,
                                            bf16* __restrict__ out) {
    int row = blockIdx.x, c = threadIdx.x;
    float x = in[(size_t)row * 256 + c];
    float s = x, s2 = x * x;
    for (int off = 32; off; off >>= 1) { s += __shfl_down(s, off); s2 += __shfl_down(s2, off); }
    __shared__ float red[8];
    int wid = c >> 6, lane = c & 63;
    if (lane == 0) { red[wid] = s; red[wid + 4] = s2; }
    __syncthreads();
    if (c == 0) { red[0] = red[0] + red[1] + red[2] + red[3]; red[4] = red[4] + red[5] + red[6] + red[7]; }
    __syncthreads();
    float mean = red[0] * (1.f / 256.f);
    float var  = fmaxf(red[4] * (1.f / 256.f) - mean * mean, 0.f);
    float rstd = rsqrtf(var + 1e-5f);
    out[(size_t)row * 256 + c] = f2b((x - mean) * rstd * g[c] + b[c]);
}

// ---------------------------------------------------------------- MFMA GEMM, dbuf global_load_lds + COUNTED vmcnt (T4)
// MODE 0: bf16 store  MODE 1: bf16 GELU store  MODE 2: += f32 residual  MODE 3: f32 store (no bias)
template <int MODE>
__global__ __launch_bounds__(256) void gemm_k(const bf16* __restrict__ A,
                                              const bf16* __restrict__ W,
                                              const float* __restrict__ bias,
                                              int M, int N, int K,
                                              float* __restrict__ res,
                                              bf16* __restrict__ outb) {
    __shared__ short As[2][128 * 32];
    __shared__ short Ws[2][128 * 32];
    int m0 = blockIdx.y * 128, n0 = blockIdx.x * 128;
    int tid = threadIdx.x;
    int lane = tid & 63, wave = tid >> 6;
    int quad = lane >> 4, m16 = lane & 15;
    int wm = (wave & 1) * 64, wn = (wave >> 1) * 64;
    int arow = tid >> 2, acol = (tid & 3) * 8;

    const bf16* Ab = A + (size_t)(m0 + arow) * K + acol;
    const bf16* A2 = Ab + (size_t)64 * K;
    const bf16* Wb = W + (size_t)(n0 + arow) * K + acol;
    const bf16* W2 = Wb + (size_t)64 * K;

    f4 acc[4][4];
    #pragma unroll
    for (int i = 0; i < 4; i++)
        #pragma unroll
        for (int j = 0; j < 4; j++) acc[i][j] = (f4){0.f, 0.f, 0.f, 0.f};

    gl16(Ab, &As[0][tid * 8]);
    gl16(A2, &As[0][2048 + tid * 8]);
    gl16(Wb, &Ws[0][tid * 8]);
    gl16(W2, &Ws[0][2048 + tid * 8]);

    int cur = 0;
    for (int k0 = 0; k0 < K; k0 += 32) {
        int nxt = cur ^ 1;
        if (k0 + 32 < K) {
            gl16(Ab + k0 + 32, &As[nxt][tid * 8]);
            gl16(A2 + k0 + 32, &As[nxt][2048 + tid * 8]);
            gl16(Wb + k0 + 32, &Ws[nxt][tid * 8]);
            gl16(W2 + k0 + 32, &Ws[nxt][2048 + tid * 8]);
            asm volatile("s_waitcnt vmcnt(4)" ::: "memory");   // cur landed; nxt in flight
        } else {
            asm volatile("s_waitcnt vmcnt(0)" ::: "memory");   // last tile: drain
        }
        __builtin_amdgcn_s_barrier();
        sh8 af[4], bf[4];
        #pragma unroll
        for (int mi = 0; mi < 4; mi++)
            af[mi] = *reinterpret_cast<const sh8*>(&As[cur][(wm + mi * 16 + m16) * 32 + quad * 8]);
        #pragma unroll
        for (int ni = 0; ni < 4; ni++)
            bf[ni] = *reinterpret_cast<const sh8*>(&Ws[cur][(wn + ni * 16 + m16) * 32 + quad * 8]);
        #pragma unroll
        for (int mi = 0; mi < 4; mi++)
            #pragma unroll
            for (int ni = 0; ni < 4; ni++)
                acc[mi][ni] = __builtin_amdgcn_mfma_f32_16x16x32_bf16(af[mi], bf[ni], acc[mi][ni], 0, 0, 0);
        __builtin_amdgcn_s_barrier();
        cur = nxt;
    }
    (void)M;

    #pragma unroll
    for (int mi = 0; mi < 4; mi++) {
        #pragma unroll
        for (int r = 0; r < 4; r++) {
            int gm = m0 + wm + mi * 16 + quad * 4 + r;
            #pragma unroll
            for (int ni = 0; ni < 4; ni++) {
                int gn = n0 + wn + ni * 16 + m16;
                float v = acc[mi][ni][r];
                if constexpr (MODE != 3) v += bias[gn];
                if constexpr (MODE == 2)      res[(size_t)gm * N + gn] += v;
                else if constexpr (MODE == 3) res[(size_t)gm * N + gn] = v;
                else if constexpr (MODE == 1) outb[(size_t)gm * N + gn] = f2b(0.5f * v * (1.0f + erff(v * 0.70710678118654752f)));
                else                          outb[(size_t)gm * N + gn] = f2b(v);
            }
        }
    }
}

// ---------------------------------------------------------------- WIDE MFMA GEMM: 512 thr, tile 128m x 256n (gemmln geometry)
// Halves A re-reads (N-blocks) and barrier-steps per FLOP vs 128x128.
// MODE 0: bf16 store  MODE 1: bf16 GELU store. grid (N/256, M/128).
template <int MODE>
__global__ __launch_bounds__(512) void gemm2_k(const bf16* __restrict__ A,
                                               const bf16* __restrict__ W,
                                               const float* __restrict__ bias,
                                               int N, int K,
                                               bf16* __restrict__ outb) {
    __shared__ short As[2][128 * 32];
    __shared__ short Ws[2][256 * 32];
    int m0 = blockIdx.y * 128, n0 = blockIdx.x * 256;
    int tid = threadIdx.x;
    int lane = tid & 63, wave = tid >> 6;
    int quad = lane >> 4, m16 = lane & 15;
    int wm = (wave >> 2) * 64, wn = (wave & 3) * 64;
    int arow = tid >> 2, acol = (tid & 3) * 8;

    const bf16* Ab = A + (size_t)(m0 + arow) * K + acol;
    const bf16* Wb = W + (size_t)(n0 + arow) * K + acol;
    const bf16* W2 = Wb + (size_t)128 * K;

    f4 acc[4][4];
    #pragma unroll
    for (int i = 0; i < 4; i++)
        #pragma unroll
        for (int j = 0; j < 4; j++) acc[i][j] = (f4){0.f, 0.f, 0.f, 0.f};

    gl16(Ab, &As[0][tid * 8]);
    gl16(Wb, &Ws[0][tid * 8]);
    gl16(W2, &Ws[0][4096 + tid * 8]);

    int cur = 0;
    for (int k0 = 0; k0 < K; k0 += 32) {
        int nxt = cur ^ 1;
        if (k0 + 32 < K) {
            gl16(Ab + k0 + 32, &As[nxt][tid * 8]);
            gl16(Wb + k0 + 32, &Ws[nxt][tid * 8]);
            gl16(W2 + k0 + 32, &Ws[nxt][4096 + tid * 8]);
            asm volatile("s_waitcnt vmcnt(3)" ::: "memory");
        } else {
            asm volatile("s_waitcnt vmcnt(0)" ::: "memory");
        }
        __builtin_amdgcn_s_barrier();
        sh8 af[4], bf[4];
        #pragma unroll
        for (int mi = 0; mi < 4; mi++)
            af[mi] = *reinterpret_cast<const sh8*>(&As[cur][(wm + mi * 16 + m16) * 32 + quad * 8]);
        #pragma unroll
        for (int ni = 0; ni < 4; ni++)
            bf[ni] = *reinterpret_cast<const sh8*>(&Ws[cur][(wn + ni * 16 + m16) * 32 + quad * 8]);
        #pragma unroll
        for (int mi = 0; mi < 4; mi++)
            #pragma unroll
            for (int ni = 0; ni < 4; ni++)
                acc[mi][ni] = __builtin_amdgcn_mfma_f32_16x16x32_bf16(af[mi], bf[ni], acc[mi][ni], 0, 0, 0);
        __builtin_amdgcn_s_barrier();
        cur = nxt;
    }

    #pragma unroll
    for (int mi = 0; mi < 4; mi++) {
        #pragma unroll
        for (int r = 0; r < 4; r++) {
            int gm = m0 + wm + mi * 16 + quad * 4 + r;
            #pragma unroll
            for (int ni = 0; ni < 4; ni++) {
                int gn = n0 + wn + ni * 16 + m16;
                float v = acc[mi][ni][r] + bias[gn];
                if constexpr (MODE == 1) outb[(size_t)gm * N + gn] = f2b(0.5f * v * (1.0f + erff(v * 0.70710678118654752f)));
                else                     outb[(size_t)gm * N + gn] = f2b(v);
            }
        }
    }
}

// ---------------------------------------------------------------- fused GEMM(N=256,K=256) + bias + residual(RMW xcat) + LayerNorm
__global__ __launch_bounds__(512) void gemmln_k(const bf16* __restrict__ A,
                                                const bf16* __restrict__ W,
                                                const float* __restrict__ bias,
                                                float* __restrict__ xcat,
                                                const float* __restrict__ g,
                                                const float* __restrict__ b,
                                                bf16* __restrict__ outb) {
    __shared__ short As[2][128 * 32];
    __shared__ short Ws[2][256 * 32];
    __shared__ float redS[128 * 4];
    __shared__ float redQ[128 * 4];
    __shared__ float stat[128 * 2];
    int m0 = blockIdx.x * 128;
    int tid = threadIdx.x;
    int lane = tid & 63, wave = tid >> 6;
    int quad = lane >> 4, m16 = lane & 15;
    int wm = (wave >> 2) * 64, wn = (wave & 3) * 64;
    int arow = tid >> 2, acol = (tid & 3) * 8;

    const bf16* Ab = A + (size_t)(m0 + arow) * 256 + acol;   // arow in 0..127
    const bf16* Wb = W + (size_t)arow * 256 + acol;
    const bf16* W2 = Wb + (size_t)128 * 256;

    f4 acc[4][4];
    #pragma unroll
    for (int i = 0; i < 4; i++)
        #pragma unroll
        for (int j = 0; j < 4; j++) acc[i][j] = (f4){0.f, 0.f, 0.f, 0.f};

    gl16(Ab, &As[0][tid * 8]);
    gl16(Wb, &Ws[0][tid * 8]);
    gl16(W2, &Ws[0][4096 + tid * 8]);

    int cur = 0;
    for (int k0 = 0; k0 < 256; k0 += 32) {
        int nxt = cur ^ 1;
        if (k0 + 32 < 256) {
            gl16(Ab + k0 + 32, &As[nxt][tid * 8]);
            gl16(Wb + k0 + 32, &Ws[nxt][tid * 8]);
            gl16(W2 + k0 + 32, &Ws[nxt][4096 + tid * 8]);
            asm volatile("s_waitcnt vmcnt(3)" ::: "memory");
        } else {
            asm volatile("s_waitcnt vmcnt(0)" ::: "memory");
        }
        __builtin_amdgcn_s_barrier();
        sh8 af[4], bf[4];
        #pragma unroll
        for (int mi = 0; mi < 4; mi++)
            af[mi] = *reinterpret_cast<const sh8*>(&As[cur][(wm + mi * 16 + m16) * 32 + quad * 8]);
        #pragma unroll
        for (int ni = 0; ni < 4; ni++)
            bf[ni] = *reinterpret_cast<const sh8*>(&Ws[cur][(wn + ni * 16 + m16) * 32 + quad * 8]);
        #pragma unroll
        for (int mi = 0; mi < 4; mi++)
            #pragma unroll
            for (int ni = 0; ni < 4; ni++)
                acc[mi][ni] = __builtin_amdgcn_mfma_f32_16x16x32_bf16(af[mi], bf[ni], acc[mi][ni], 0, 0, 0);
        __builtin_amdgcn_s_barrier();
        cur = nxt;
    }

    #pragma unroll
    for (int mi = 0; mi < 4; mi++) {
        #pragma unroll
        for (int r = 0; r < 4; r++) {
            int lr = wm + mi * 16 + quad * 4 + r;
            int gm = m0 + lr;
            float ps = 0.f, pq = 0.f;
            #pragma unroll
            for (int ni = 0; ni < 4; ni++) {
                int gc = wn + ni * 16 + m16;
                float v = acc[mi][ni][r] + bias[gc] + xcat[(size_t)gm * 256 + gc];
                acc[mi][ni][r] = v;
                ps += v; pq += v * v;
            }
            ps += __shfl_xor(ps, 1); pq += __shfl_xor(pq, 1);
            ps += __shfl_xor(ps, 2); pq += __shfl_xor(pq, 2);
            ps += __shfl_xor(ps, 4); pq += __shfl_xor(pq, 4);
            ps += __shfl_xor(ps, 8); pq += __shfl_xor(pq, 8);
            if (m16 == 0) { redS[lr * 4 + (wave & 3)] = ps; redQ[lr * 4 + (wave & 3)] = pq; }
        }
    }
    __syncthreads();
    if (tid < 128) {
        float s = redS[tid * 4] + redS[tid * 4 + 1] + redS[tid * 4 + 2] + redS[tid * 4 + 3];
        float q = redQ[tid * 4] + redQ[tid * 4 + 1] + redQ[tid * 4 + 2] + redQ[tid * 4 + 3];
        float mean = s * (1.f / 256.f);
        float var  = fmaxf(q * (1.f / 256.f) - mean * mean, 0.f);
        stat[tid * 2]     = mean;
        stat[tid * 2 + 1] = rsqrtf(var + 1e-5f);
    }
    __syncthreads();
    #pragma unroll
    for (int mi = 0; mi < 4; mi++) {
        #pragma unroll
        for (int r = 0; r < 4; r++) {
            int lr = wm + mi * 16 + quad * 4 + r;
            int gm = m0 + lr;
            float mean = stat[lr * 2], rstd = stat[lr * 2 + 1];
            #pragma unroll
            for (int ni = 0; ni < 4; ni++) {
                int gc = wn + ni * 16 + m16;
                float v = acc[mi][ni][r];
                xcat[(size_t)gm * 256 + gc] = v;
                outb[(size_t)gm * 256 + gc] = f2b((v - mean) * rstd * g[gc] + b[gc]);
            }
        }
    }
}

// ---------------------------------------------------------------- fused GEMM(N=256) + bias + residual(read xcat) + split write
__global__ __launch_bounds__(256) void gemmsplit_k(const bf16* __restrict__ A,
                                                   const bf16* __restrict__ W,
                                                   const float* __restrict__ bias,
                                                   int K,
                                                   const float* __restrict__ res,
                                                   float* __restrict__ out) {
    __shared__ short As[2][128 * 32];
    __shared__ short Ws[2][128 * 32];
    int m0 = blockIdx.y * 128, n0 = blockIdx.x * 128;
    int tid = threadIdx.x;
    int lane = tid & 63, wave = tid >> 6;
    int quad = lane >> 4, m16 = lane & 15;
    int wm = (wave & 1) * 64, wn = (wave >> 1) * 64;
    int arow = tid >> 2, acol = (tid & 3) * 8;

    const bf16* Ab = A + (size_t)(m0 + arow) * K + acol;
    const bf16* A2 = Ab + (size_t)64 * K;
    const bf16* Wb = W + (size_t)(n0 + arow) * K + acol;
    const bf16* W2 = Wb + (size_t)64 * K;

    f4 acc[4][4];
    #pragma unroll
    for (int i = 0; i < 4; i++)
        #pragma unroll
        for (int j = 0; j < 4; j++) acc[i][j] = (f4){0.f, 0.f, 0.f, 0.f};

    gl16(Ab, &As[0][tid * 8]);
    gl16(A2, &As[0][2048 + tid * 8]);
    gl16(Wb, &Ws[0][tid * 8]);
    gl16(W2, &Ws[0][2048 + tid * 8]);

    int cur = 0;
    for (int k0 = 0; k0 < K; k0 += 32) {
        int nxt = cur ^ 1;
        if (k0 + 32 < K) {
            gl16(Ab + k0 + 32, &As[nxt][tid * 8]);
            gl16(A2 + k0 + 32, &As[nxt][2048 + tid * 8]);
            gl16(Wb + k0 + 32, &Ws[nxt][tid * 8]);
            gl16(W2 + k0 + 32, &Ws[nxt][2048 + tid * 8]);
            asm volatile("s_waitcnt vmcnt(4)" ::: "memory");
        } else {
            asm volatile("s_waitcnt vmcnt(0)" ::: "memory");
        }
        __builtin_amdgcn_s_barrier();
        sh8 af[4], bf[4];
        #pragma unroll
        for (int mi = 0; mi < 4; mi++)
            af[mi] = *reinterpret_cast<const sh8*>(&As[cur][(wm + mi * 16 + m16) * 32 + quad * 8]);
        #pragma unroll
        for (int ni = 0; ni < 4; ni++)
            bf[ni] = *reinterpret_cast<const sh8*>(&Ws[cur][(wn + ni * 16 + m16) * 32 + quad * 8]);
        #pragma unroll
        for (int mi = 0; mi < 4; mi++)
            #pragma unroll
            for (int ni = 0; ni < 4; ni++)
                acc[mi][ni] = __builtin_amdgcn_mfma_f32_16x16x32_bf16(af[mi], bf[ni], acc[mi][ni], 0, 0, 0);
        __builtin_amdgcn_s_barrier();
        cur = nxt;
    }

    #pragma unroll
    for (int mi = 0; mi < 4; mi++) {
        #pragma unroll
        for (int r = 0; r < 4; r++) {
            int gm = m0 + wm + mi * 16 + quad * 4 + r;
            int w = gm / 520, p = gm - w * 520;
            size_t drow = (p >= 8) ? (size_t)(w * 512 + p - 8) : (size_t)(32768 + w * 8 + p);
            #pragma unroll
            for (int ni = 0; ni < 4; ni++) {
                int gn = n0 + wn + ni * 16 + m16;
                float v = acc[mi][ni][r] + bias[gn] + res[(size_t)gm * 256 + gn];
                out[drow * 256 + gn] = v;
            }
        }
    }
}

// ---------------------------------------------------------------- MFMA flash attention, fixed-max softmax (exp2 pre-folded)
// 512 threads (8 waves). qs in {0,1}: one full pair-unit per wave. qs==2: runt kt-split.
// Bias via reversed per-h CPB table (L1-resident): bias[r] = tabr[qrc + kidx + r].
#define VSTR 548   /* shorts; step 18 mod 32 -> max 2-way (free), 8B-aligned */
#define SC2   0.25503575360579045f   /* SCALE_QK * log2(e) */
#define CNB  (-34.62468098133512f)   /* -24 * log2(e) */
#define NEGB (-1.0e30f)
__device__ __forceinline__ int cpb_kidx(int kl) {
    return (kl >> 6) * 225 + ((kl >> 3) & 7) * 15 + (kl & 7);
}
__device__ __forceinline__ int cpb_qconst(int ql) {
    return ((ql >> 6) + 7) * 225 + (((ql >> 3) & 7) + 7) * 15 + ((ql & 7) + 7);
}
// qrc = 3374 - cpb_qconst(q)
__device__ __forceinline__ f4 bias_tab(const float* __restrict__ tabh, bool vq, int qrc,
                                       int tg, int kidx, int N, int glob) {
    if (tg >= N) return (f4){NEGB, NEGB, NEGB, NEGB};
    if (vq && tg >= glob) {
        f4 v;
        __builtin_memcpy(&v, tabh + qrc + kidx, 16);
        return v;
    }
    return (f4){CNB, CNB, CNB, CNB};
}
__global__ __launch_bounds__(512) void flash_k(const bf16* __restrict__ qkv,
                                               const float* __restrict__ tab,
                                               bf16* __restrict__ out,
                                               int N, int glob) {
    int wh = blockIdx.x, w = wh >> 3, h = wh & 7;
    int qs = blockIdx.y;
    int tid = threadIdx.x;
    int lane = tid & 63, wave = tid >> 6;
    int quad = lane >> 4, qcol = lane & 15;
    const int NT32 = (N + 31) & ~31;
    const float* __restrict__ tabh = tab + h * 3375;

    __shared__ __align__(16) char smem[32 * VSTR * 2];   // Vt; runt reduce aliases it
    bf16* Vt = reinterpret_cast<bf16*>(smem);
#if !HAS_MFMA16
    __shared__ float Ps[8][16 * 17];
#endif

    for (int i = tid; i < NT32 * 4; i += 512) {
        int tok = i >> 2, seg = i & 3;
        if (tok < N) {
            const bf16* vp = qkv + ((size_t)(w * N + tok)) * 768 + 512 + h * 32 + seg * 8;
            bf16x8 vv = *reinterpret_cast<const bf16x8*>(vp);
            #pragma unroll
            for (int e = 0; e < 8; e++) Vt[(seg * 8 + e) * VSTR + tok] = vv.v[e];
        } else {
            bf16 z = f2b(0.f);
            #pragma unroll
            for (int e = 0; e < 8; e++) Vt[(seg * 8 + e) * VSTR + tok] = z;
        }
    }
    __syncthreads();

    const bf16* qbase = qkv + ((size_t)w * N) * 768 + h * 32;
    const bf16* kbase = qbase + 256;
    int nqt = (N + 15) >> 4, nkt = NT32 >> 5;
    int nfull = nqt >> 1;            // 16 for both call sites

    if (qs < 2) {
        int u = wave + 8 * qs;       // exactly one full pair unit per wave
        if (u < nfull) {
            int qA = u * 32 + qcol;  // always < N
            int qB = qA + 16;
            sh8 qfA = *reinterpret_cast<const sh8*>(qbase + (size_t)qA * 768 + quad * 8);
            sh8 qfB = *reinterpret_cast<const sh8*>(qbase + (size_t)qB * 768 + quad * 8);
            f4 O0A = {0.f,0.f,0.f,0.f}, O1A = {0.f,0.f,0.f,0.f};
            f4 O0B = {0.f,0.f,0.f,0.f}, O1B = {0.f,0.f,0.f,0.f};
            float lA = 0.f, lB = 0.f;
            bool vA = (qA >= glob);
            bool vB = (qB >= glob);
            int qrcA = vA ? (3374 - cpb_qconst(qA - glob)) : 0;
            int qrcB = vB ? (3374 - cpb_qconst(qB - glob)) : 0;

            // prefetch K frags for kt=0
            sh8 kf0, kf1;
            {
                int k0 = qcol, k1 = 16 + qcol;
                kf0 = *reinterpret_cast<const sh8*>(kbase + (size_t)((k0 < N) ? k0 : (N - 1)) * 768 + quad * 8);
                kf1 = *reinterpret_cast<const sh8*>(kbase + (size_t)((k1 < N) ? k1 : (N - 1)) * 768 + quad * 8);
            }

            for (int kt = 0; kt < nkt; kt++) {
                int bt = kt * 32;
                sh8 c0 = kf0, c1 = kf1;
                if (kt + 1 < nkt) {
                    int n0 = bt + 32 + qcol, n1 = bt + 48 + qcol;
                    kf0 = *reinterpret_cast<const sh8*>(kbase + (size_t)((n0 < N) ? n0 : (N - 1)) * 768 + quad * 8);
                    kf1 = *reinterpret_cast<const sh8*>(kbase + (size_t)((n1 < N) ? n1 : (N - 1)) * 768 + quad * 8);
                }
                f4 z = {0.f, 0.f, 0.f, 0.f};
                f4 s0A = __builtin_amdgcn_mfma_f32_16x16x32_bf16(c0, qfA, z, 0, 0, 0);
                f4 s1A = __builtin_amdgcn_mfma_f32_16x16x32_bf16(c1, qfA, z, 0, 0, 0);
                f4 s0B = __builtin_amdgcn_mfma_f32_16x16x32_bf16(c0, qfB, z, 0, 0, 0);
                f4 s1B = __builtin_amdgcn_mfma_f32_16x16x32_bf16(c1, qfB, z, 0, 0, 0);

                int tg0 = bt + quad * 4, tg1 = tg0 + 16;
                int kidx0 = cpb_kidx(tg0 - glob);
                int kidx1 = cpb_kidx(tg1 - glob);
                f4 bb0A = bias_tab(tabh, vA, qrcA, tg0, kidx0, N, glob);
                f4 bb1A = bias_tab(tabh, vA, qrcA, tg1, kidx1, N, glob);
                f4 bb0B = bias_tab(tabh, vB, qrcB, tg0, kidx0, N, glob);
                f4 bb1B = bias_tab(tabh, vB, qrcB, tg1, kidx1, N, glob);

                float pA[8], pB[8];
                #pragma unroll
                for (int r = 0; r < 4; r++) {
                    pA[r]     = EXP2(fmaf(s0A[r], SC2, bb0A[r]));
                    pA[4 + r] = EXP2(fmaf(s1A[r], SC2, bb1A[r]));
                    pB[r]     = EXP2(fmaf(s0B[r], SC2, bb0B[r]));
                    pB[4 + r] = EXP2(fmaf(s1B[r], SC2, bb1B[r]));
                }
                #pragma unroll
                for (int r = 0; r < 8; r++) { lA += pA[r]; lB += pB[r]; }

#if HAS_MFMA16
                sh4 v00 = *reinterpret_cast<const sh4*>(&Vt[qcol * VSTR + bt + quad * 4]);
                sh4 v10 = *reinterpret_cast<const sh4*>(&Vt[qcol * VSTR + bt + 16 + quad * 4]);
                sh4 v01 = *reinterpret_cast<const sh4*>(&Vt[(qcol + 16) * VSTR + bt + quad * 4]);
                sh4 v11 = *reinterpret_cast<const sh4*>(&Vt[(qcol + 16) * VSTR + bt + 16 + quad * 4]);
                sh4 pf0A, pf1A, pf0B, pf1B;
                #pragma unroll
                for (int r = 0; r < 4; r++) {
                    pf0A[r] = bfs(pA[r]); pf1A[r] = bfs(pA[4 + r]);
                    pf0B[r] = bfs(pB[r]); pf1B[r] = bfs(pB[4 + r]);
                }
                O0A = __builtin_amdgcn_mfma_f32_16x16x16bf16_1k(v00, pf0A, O0A, 0, 0, 0);
                O0A = __builtin_amdgcn_mfma_f32_16x16x16bf16_1k(v10, pf1A, O0A, 0, 0, 0);
                O1A = __builtin_amdgcn_mfma_f32_16x16x16bf16_1k(v01, pf0A, O1A, 0, 0, 0);
                O1A = __builtin_amdgcn_mfma_f32_16x16x16bf16_1k(v11, pf1A, O1A, 0, 0, 0);
                O0B = __builtin_amdgcn_mfma_f32_16x16x16bf16_1k(v00, pf0B, O0B, 0, 0, 0);
                O0B = __builtin_amdgcn_mfma_f32_16x16x16bf16_1k(v10, pf1B, O0B, 0, 0, 0);
                O1B = __builtin_amdgcn_mfma_f32_16x16x16bf16_1k(v01, pf0B, O1B, 0, 0, 0);
                O1B = __builtin_amdgcn_mfma_f32_16x16x16bf16_1k(v11, pf1B, O1B, 0, 0, 0);
#else
                for (int t = 0; t < 2; t++) {
                    const float* ph = t ? pB : pA;
                    for (int half = 0; half < 2; half++) {
                        #pragma unroll
                        for (int r = 0; r < 4; r++) Ps[wave][(quad * 4 + r) * 17 + qcol] = ph[half * 4 + r];
                        __builtin_amdgcn_wave_barrier();
                        sh8 pbig, va, vb;
                        #pragma unroll
                        for (int j = 0; j < 8; j++) {
                            int tl = quad * 8 + j;
                            float pv = (quad < 2) ? Ps[wave][tl * 17 + qcol] : 0.f;
                            pbig[j] = bfs(pv);
                            bf16 a0 = (quad < 2) ? Vt[qcol * VSTR + bt + half * 16 + tl] : f2b(0.f);
                            bf16 a1 = (quad < 2) ? Vt[(qcol + 16) * VSTR + bt + half * 16 + tl] : f2b(0.f);
                            short t0, t1;
                            __builtin_memcpy(&t0, &a0, 2); __builtin_memcpy(&t1, &a1, 2);
                            va[j] = t0; vb[j] = t1;
                        }
                        if (t == 0) {
                            O0A = __builtin_amdgcn_mfma_f32_16x16x32_bf16(va, pbig, O0A, 0, 0, 0);
                            O1A = __builtin_amdgcn_mfma_f32_16x16x32_bf16(vb, pbig, O1A, 0, 0, 0);
                        } else {
                            O0B = __builtin_amdgcn_mfma_f32_16x16x32_bf16(va, pbig, O0B, 0, 0, 0);
                            O1B = __builtin_amdgcn_mfma_f32_16x16x32_bf16(vb, pbig, O1B, 0, 0, 0);
                        }
                        __builtin_amdgcn_wave_barrier();
                    }
                }
#endif
            }

            lA += __shfl_xor(lA, 16); lA += __shfl_xor(lA, 32);
            lB += __shfl_xor(lB, 16); lB += __shfl_xor(lB, 32);
            float rlA = 1.f / lA, rlB = 1.f / lB;
            {
                bf16x4 o0, o1;
                #pragma unroll
                for (int r = 0; r < 4; r++) { o0.v[r] = f2b(O0A[r] * rlA); o1.v[r] = f2b(O1A[r] * rlA); }
                bf16* op = out + ((size_t)(w * N + qA)) * 256 + h * 32 + quad * 4;
                *reinterpret_cast<bf16x4*>(op)      = o0;
                *reinterpret_cast<bf16x4*>(op + 16) = o1;
            }
            {
                bf16x4 o0, o1;
                #pragma unroll
                for (int r = 0; r < 4; r++) { o0.v[r] = f2b(O0B[r] * rlB); o1.v[r] = f2b(O1B[r] * rlB); }
                bf16* op = out + ((size_t)(w * N + qB)) * 256 + h * 32 + quad * 4;
                *reinterpret_cast<bf16x4*>(op)      = o0;
                *reinterpret_cast<bf16x4*>(op + 16) = o1;
            }
        }
    } else {
        // ---- runt-only block: tile nqt-1, kt-split across the 8 waves ----
        int rt = nqt - 1;
        int qA = rt * 16 + qcol;            // may be >= N
        int qrA = (qA < N) ? qA : (N - 1);
        sh8 qfA = *reinterpret_cast<const sh8*>(qbase + (size_t)qrA * 768 + quad * 8);
        f4 O0 = {0.f,0.f,0.f,0.f}, O1 = {0.f,0.f,0.f,0.f};
        float l = 0.f;
        bool vA = (qA >= glob) && (qA < N);
        int qrcA = vA ? (3374 - cpb_qconst(qA - glob)) : 0;

        for (int kt = wave; kt < nkt; kt += 8) {
            int bt = kt * 32;
            int k0 = bt + qcol, k1 = bt + 16 + qcol;
            sh8 c0 = *reinterpret_cast<const sh8*>(kbase + (size_t)((k0 < N) ? k0 : (N - 1)) * 768 + quad * 8);
            sh8 c1 = *reinterpret_cast<const sh8*>(kbase + (size_t)((k1 < N) ? k1 : (N - 1)) * 768 + quad * 8);
            f4 z = {0.f, 0.f, 0.f, 0.f};
            f4 s0 = __builtin_amdgcn_mfma_f32_16x16x32_bf16(c0, qfA, z, 0, 0, 0);
            f4 s1 = __builtin_amdgcn_mfma_f32_16x16x32_bf16(c1, qfA, z, 0, 0, 0);

            int tg0 = bt + quad * 4, tg1 = tg0 + 16;
            int kidx0 = cpb_kidx(tg0 - glob);
            int kidx1 = cpb_kidx(tg1 - glob);
            f4 bb0 = bias_tab(tabh, vA, qrcA, tg0, kidx0, N, glob);
            f4 bb1 = bias_tab(tabh, vA, qrcA, tg1, kidx1, N, glob);

            float p[8];
            #pragma unroll
            for (int r = 0; r < 4; r++) {
                p[r]     = EXP2(fmaf(s0[r], SC2, bb0[r]));
                p[4 + r] = EXP2(fmaf(s1[r], SC2, bb1[r]));
            }
            #pragma unroll
            for (int r = 0; r < 8; r++) l += p[r];

#if HAS_MFMA16
            sh4 v00 = *reinterpret_cast<const sh4*>(&Vt[qcol * VSTR + bt + quad * 4]);
            sh4 v10 = *reinterpret_cast<const sh4*>(&Vt[qcol * VSTR + bt + 16 + quad * 4]);
            sh4 v01 = *reinterpret_cast<const sh4*>(&Vt[(qcol + 16) * VSTR + bt + quad * 4]);
            sh4 v11 = *reinterpret_cast<const sh4*>(&Vt[(qcol + 16) * VSTR + bt + 16 + quad * 4]);
            sh4 pf0, pf1;
            #pragma unroll
            for (int r = 0; r < 4; r++) { pf0[r] = bfs(p[r]); pf1[r] = bfs(p[4 + r]); }
            O0 = __builtin_amdgcn_mfma_f32_16x16x16bf16_1k(v00, pf0, O0, 0, 0, 0);
            O0 = __builtin_amdgcn_mfma_f32_16x16x16bf16_1k(v10, pf1, O0, 0, 0, 0);
            O1 = __builtin_amdgcn_mfma_f32_16x16x16bf16_1k(v01, pf0, O1, 0, 0, 0);
            O1 = __builtin_amdgcn_mfma_f32_16x16x16bf16_1k(v11, pf1, O1, 0, 0, 0);
#else
            for (int half = 0; half < 2; half++) {
                #pragma unroll
                for (int r = 0; r < 4; r++) Ps[wave][(quad * 4 + r) * 17 + qcol] = p[half * 4 + r];
                __builtin_amdgcn_wave_barrier();
                sh8 pbig, va, vb;
                #pragma unroll
                for (int j = 0; j < 8; j++) {
                    int tl = quad * 8 + j;
                    float pv = (quad < 2) ? Ps[wave][tl * 17 + qcol] : 0.f;
                    pbig[j] = bfs(pv);
                    bf16 a0 = (quad < 2) ? Vt[qcol * VSTR + bt + half * 16 + tl] : f2b(0.f);
                    bf16 a1 = (quad < 2) ? Vt[(qcol + 16) * VSTR + bt + half * 16 + tl] : f2b(0.f);
                    short t0, t1;
                    __builtin_memcpy(&t0, &a0, 2); __builtin_memcpy(&t1, &a1, 2);
                    va[j] = t0; vb[j] = t1;
                }
                O0 = __builtin_amdgcn_mfma_f32_16x16x32_bf16(va, pbig, O0, 0, 0, 0);
                O1 = __builtin_amdgcn_mfma_f32_16x16x32_bf16(vb, pbig, O1, 0, 0, 0);
                __builtin_amdgcn_wave_barrier();
            }
#endif
        }

        // all Vt reads done -> safe to alias the reduce buffer over Vt
        __syncthreads();
        float (*red)[64][9] = reinterpret_cast<float (*)[64][9]>(smem);
        #pragma unroll
        for (int r = 0; r < 4; r++) { red[wave][lane][r] = O0[r]; red[wave][lane][4 + r] = O1[r]; }
        red[wave][lane][8] = l;
        __syncthreads();

        if (wave == 0) {
            f4 O0s = {0.f,0.f,0.f,0.f}, O1s = {0.f,0.f,0.f,0.f};
            float ls = 0.f;
            for (int v = 0; v < 8; v++) {
                #pragma unroll
                for (int r = 0; r < 4; r++) { O0s[r] += red[v][lane][r]; O1s[r] += red[v][lane][4 + r]; }
                ls += red[v][lane][8];
            }
            ls += __shfl_xor(ls, 16); ls += __shfl_xor(ls, 32);
            float rl = 1.f / ls;
            if (qA < N) {
                bf16x4 o0, o1;
                #pragma unroll
                for (int r = 0; r < 4; r++) { o0.v[r] = f2b(O0s[r] * rl); o1.v[r] = f2b(O1s[r] * rl); }
                bf16* op = out + ((size_t)(w * N + qA)) * 256 + h * 32 + quad * 4;
                *reinterpret_cast<bf16x4*>(op)      = o0;
                *reinterpret_cast<bf16x4*>(op + 16) = o1;
            }
        }
    }
}

// ---------------------------------------------------------------- xcat build + LN1 fused: writes xcat f32 and xln bf16
__global__ __launch_bounds__(256) void xcatln_k(const float* __restrict__ x_in,
                                                const float* __restrict__ pe,
                                                const float* __restrict__ ct2,
                                                const float* __restrict__ g,
                                                const float* __restrict__ b,
                                                float* __restrict__ xcat,
                                                bf16* __restrict__ xln) {
    int row = blockIdx.x, w = row / 520, p = row - w * 520, c = threadIdx.x;
    float v;
    if (p < 8) {
        int P = w >> 4, Q = (w >> 2) & 3, R = w & 3;
        int S = p >> 2, T = (p >> 1) & 1, U = p & 1;
        int t = P * 128 + S * 64 + Q * 16 + T * 8 + R * 2 + U;
        v = ct2[(size_t)t * 256 + c];
    } else {
        int t = p - 8;
        v = x_in[((size_t)w * 512 + t) * 256 + c] + pe[(size_t)t * 256 + c];
    }
    xcat[(size_t)row * 256 + c] = v;
    float s = v, s2 = v * v;
    for (int off = 32; off; off >>= 1) { s += __shfl_down(s, off); s2 += __shfl_down(s2, off); }
    __shared__ float red[8];
    int wid = c >> 6, lane = c & 63;
    if (lane == 0) { red[wid] = s; red[wid + 4] = s2; }
    __syncthreads();
    if (c == 0) { red[0] = red[0] + red[1] + red[2] + red[3]; red[4] = red[4] + red[5] + red[6] + red[7]; }
    __syncthreads();
    float mean = red[0] * (1.f / 256.f);
    float var  = fmaxf(red[4] * (1.f / 256.f) - mean * mean, 0.f);
    float rstd = rsqrtf(var + 1e-5f);
    xln[(size_t)row * 256 + c] = f2b((v - mean) * rstd * g[c] + b[c]);
}

// ---------------------------------------------------------------- xcat build (legacy slab path)
__global__ __launch_bounds__(256) void xcatbuild_k(const float* __restrict__ x_in,
                                                   const float* __restrict__ pe,
                                                   const float* __restrict__ ct2,
                                                   float* __restrict__ xcat) {
    int row = blockIdx.x, w = row / 520, p = row - w * 520, c = threadIdx.x;
    float v;
    if (p < 8) {
        int P = w >> 4, Q = (w >> 2) & 3, R = w & 3;
        int S = p >> 2, T = (p >> 1) & 1, U = p & 1;
        int t = P * 128 + S * 64 + Q * 16 + T * 8 + R * 2 + U;
        v = ct2[(size_t)t * 256 + c];
    } else {
        int t = p - 8;
        v = x_in[((size_t)w * 512 + t) * 256 + c] + pe[(size_t)t * 256 + c];
    }
    xcat[(size_t)row * 256 + c] = v;
}

// ---------------------------------------------------------------- output split (legacy slab path)
__global__ __launch_bounds__(256) void outbuild_k(const float* __restrict__ xcat,
                                                  float* __restrict__ out) {
    int row = blockIdx.x, w = row / 520, p = row - w * 520, c = threadIdx.x;
    float v = xcat[(size_t)row * 256 + c];
    if (p >= 8) out[((size_t)(w * 512) + (p - 8)) * 256 + c] = v;
    else        out[(size_t)8388608 + ((size_t)(w * 8) + p) * 256 + c] = v;
}

// ----------------------------------------------------------------
extern "C" void kernel_launch(void* const* d_in, const int* in_sizes, int n_in,
                              void* d_out, int out_size, void* d_ws, size_t ws_size,
                              hipStream_t stream) {
    const float* x          = (const float*)d_in[0];
    const float* ct         = (const float*)d_in[1];
    const float* pe_w1      = (const float*)d_in[2];
    const float* pe_b1      = (const float*)d_in[3];
    const float* pe_w2      = (const float*)d_in[4];
    const float* hpe_w1     = (const float*)d_in[5];
    const float* hpe_b1     = (const float*)d_in[6];
    const float* hpe_w2     = (const float*)d_in[7];
    const float* hat_n1_g   = (const float*)d_in[8];
    const float* hat_n1_b   = (const float*)d_in[9];
    const float* hat_qkv_w  = (const float*)d_in[10];
    const float* hat_qkv_b  = (const float*)d_in[11];
    const float* hat_proj_w = (const float*)d_in[12];
    const float* hat_proj_b = (const float*)d_in[13];
    const float* hat_cpb_w1 = (const float*)d_in[14];
    const float* hat_cpb_b1 = (const float*)d_in[15];
    const float* hat_cpb_w2 = (const float*)d_in[16];
    const float* hat_n2_g   = (const float*)d_in[17];
    const float* hat_n2_b   = (const float*)d_in[18];
    const float* hat_fc1_w  = (const float*)d_in[19];
    const float* hat_fc1_b  = (const float*)d_in[20];
    const float* hat_fc2_w  = (const float*)d_in[21];
    const float* hat_fc2_b  = (const float*)d_in[22];
    const float* n1_g       = (const float*)d_in[23];
    const float* n1_b       = (const float*)d_in[24];
    const float* qkv_w      = (const float*)d_in[25];
    const float* qkv_b      = (const float*)d_in[26];
    const float* proj_w     = (const float*)d_in[27];
    const float* proj_b     = (const float*)d_in[28];
    const float* cpb_w1     = (const float*)d_in[29];
    const float* cpb_b1     = (const float*)d_in[30];
    const float* cpb_w2     = (const float*)d_in[31];
    const float* n2_g       = (const float*)d_in[32];
    const float* n2_b       = (const float*)d_in[33];
    const float* fc1_w      = (const float*)d_in[34];
    const float* fc1_b      = (const float*)d_in[35];
    const float* fc2_w      = (const float*)d_in[36];
    const float* fc2_b      = (const float*)d_in[37];
    (void)in_sizes; (void)n_in; (void)out_size;

    char* base = (char*)d_ws;
    size_t off = 0;
    auto alloc = [&](size_t bytes) -> void* {
        void* p = base + off;
        off += (bytes + 255) & ~(size_t)255;
        return p;
    };
    // persistent
    float* pe        = (float*)alloc(512 * 256 * 4);
    float* hpe       = (float*)alloc(512 * 256 * 4);
    float* tab_hat   = (float*)alloc(8 * 3375 * 4);   // per-h folded+reversed CPB tables
    float* tab2      = (float*)alloc(8 * 3375 * 4);
    float* ct0       = (float*)alloc(512 * 256 * 4);
    bf16* wb_hqkv  = (bf16*)alloc(768 * 256 * 2);
    bf16* wb_hproj = (bf16*)alloc(256 * 256 * 2);
    bf16* wb_hfc1  = (bf16*)alloc(1024 * 256 * 2);
    bf16* wb_hfc2  = (bf16*)alloc(256 * 1024 * 2);
    bf16* wb_qkv   = (bf16*)alloc(768 * 256 * 2);
    bf16* wb_proj  = (bf16*)alloc(256 * 256 * 2);
    bf16* wb_fc1   = (bf16*)alloc(1024 * 256 * 2);
    bf16* wb_fc2   = (bf16*)alloc(256 * 1024 * 2);
    bf16* wb_pew2  = (bf16*)alloc(256 * 512 * 2);
    bf16* wb_hpew2 = (bf16*)alloc(256 * 512 * 2);
    size_t zstart = off;
    // phase-1 temporaries
    bf16*  hidA      = (bf16*)alloc(512 * 512 * 2);
    bf16*  hidB      = (bf16*)alloc(512 * 512 * 2);
    off = zstart;
    // hat-phase temporaries — dead before xcat is written
    bf16*  hct_ln    = (bf16*)alloc(512 * 256 * 2);
    bf16*  hqkv      = (bf16*)alloc(512 * 768 * 2);
    bf16*  hat_attn  = (bf16*)alloc(512 * 256 * 2);
    bf16*  hat_hid   = (bf16*)alloc(512 * 1024 * 2);
    // main-phase buffers overlay hat temporaries; slab count gated on ws_size
    off = zstart;
    float* xcat      = (float*)alloc((size_t)64 * 520 * 256 * 4);   // 34.1 MB
    const int S     = (ws_size >= (size_t)150 * 1024 * 1024) ? 1 : 4;
    const int rows  = 33280 / S;
    const int wins  = 64 / S;
    bf16*  xln_b     = (bf16*)alloc((size_t)rows * 256 * 2);
    char*  region_qa = (char*)alloc((size_t)rows * 1024 * 2);       // qkv+attn, or MLP hidden
    bf16*  qkv_b_    = (bf16*)region_qa;
    bf16*  attn_b    = (bf16*)(region_qa + (size_t)rows * 768 * 2);
    bf16*  hidden    = (bf16*)region_qa;

    // weight conversion (one launch)
    wcvt10_k<<<dim3(1024, 10), 256, 0, stream>>>(hat_qkv_w, hat_proj_w, hat_fc1_w, hat_fc2_w,
                                                 qkv_w, proj_w, fc1_w, fc2_w, pe_w2, hpe_w2,
                                                 wb_hqkv, wb_hproj, wb_hfc1, wb_hfc2,
                                                 wb_qkv, wb_proj, wb_fc1, wb_fc2, wb_pew2, wb_hpew2);

    // pos-emb: hidden build + MFMA gemm (M=512,N=256,K=512, f32 store)
    hidbuild_k<<<dim3(512, 2), 256, 0, stream>>>(pe_w1, pe_b1, hpe_w1, hpe_b1, hidA, hidB);
    gemm_k<3><<<dim3(2, 4), 256, 0, stream>>>(hidA, wb_pew2,  nullptr, 512, 256, 512, pe,  nullptr);
    gemm_k<3><<<dim3(2, 4), 256, 0, stream>>>(hidB, wb_hpew2, nullptr, 512, 256, 512, hpe, nullptr);

    // CPB tables (per-h folded + reversed; no bias materialization needed)
    cpbtab_k<<<dim3(3375, 2), 512, 0, stream>>>(hat_cpb_w1, hat_cpb_b1, hat_cpb_w2, tab_hat,
                                                cpb_w1, cpb_b1, cpb_w2, tab2);

    // hat branch (512 tokens, 1 window, glob=0; nqt=32 -> no runt, qs in {0,1})
    ct0ln_k<<<512, 256, 0, stream>>>(ct, hpe, hat_n1_g, hat_n1_b, ct0, hct_ln);
    gemm_k<0><<<dim3(6, 4), 256, 0, stream>>>(hct_ln, wb_hqkv, hat_qkv_b, 512, 768, 256, nullptr, hqkv);
    flash_k<<<dim3(8, 2), 512, 0, stream>>>(hqkv, tab_hat, hat_attn, 512, 0);
    gemmln_k<<<4, 512, 0, stream>>>(hat_attn, wb_hproj, hat_proj_b, ct0, hat_n2_g, hat_n2_b, hct_ln);
    gemm_k<1><<<dim3(8, 4), 256, 0, stream>>>(hct_ln, wb_hfc1, hat_fc1_b, 512, 1024, 256, nullptr, hat_hid);
    gemm_k<2><<<dim3(2, 4), 256, 0, stream>>>(hat_hid, wb_hfc2, hat_fc2_b, 512, 256, 1024, ct0, nullptr);

    if (S == 1) {
        // fused pipeline: concat+LN1, qkv(wide), flash, proj+res+LN2, fc1(wide GELU), fc2+res+split
        xcatln_k<<<33280, 256, 0, stream>>>(x, pe, ct0, n1_g, n1_b, xcat, xln_b);
        gemm2_k<0><<<dim3(3, 260), 512, 0, stream>>>(xln_b, wb_qkv, qkv_b, 768, 256, qkv_b_);
        flash_k<<<dim3(512, 3), 512, 0, stream>>>(qkv_b_, tab2, attn_b, 520, 8);
        gemmln_k<<<260, 512, 0, stream>>>(attn_b, wb_proj, proj_b, xcat, n2_g, n2_b, xln_b);
        gemm2_k<1><<<dim3(4, 260), 512, 0, stream>>>(xln_b, wb_fc1, fc1_b, 1024, 256, hidden);
        gemmsplit_k<<<dim3(2, 260), 256, 0, stream>>>(hidden, wb_fc2, fc2_b, 1024, xcat, (float*)d_out);
    } else {
        // legacy slab path
        xcatbuild_k<<<33280, 256, 0, stream>>>(x, pe, ct0, xcat);
        for (int s = 0; s < S; s++) {
            float* xc = xcat + (size_t)s * rows * 256;
            ln_k<<<rows, 256, 0, stream>>>(xc, n1_g, n1_b, xln_b);
            gemm_k<0><<<dim3(6, rows / 128), 256, 0, stream>>>(xln_b, wb_qkv, qkv_b, rows, 768, 256, nullptr, qkv_b_);
            flash_k<<<dim3(wins * 8, 3), 512, 0, stream>>>(qkv_b_, tab2, attn_b, 520, 8);
            gemm_k<2><<<dim3(2, rows / 128), 256, 0, stream>>>(attn_b, wb_proj, proj_b, rows, 256, 256, xc, nullptr);
        }
        for (int s = 0; s < S; s++) {
            float* xc = xcat + (size_t)s * rows * 256;
            ln_k<<<rows, 256, 0, stream>>>(xc, n2_g, n2_b, xln_b);
            gemm_k<1><<<dim3(8, rows / 128), 256, 0, stream>>>(xln_b, wb_fc1, fc1_b, rows, 1024, 256, nullptr, hidden);
            gemm_k<2><<<dim3(2, rows / 128), 256, 0, stream>>>(hidden, wb_fc2, fc2_b, rows, 256, 1024, xc, nullptr);
        }
        outbuild_k<<<33280, 256, 0, stream>>>(xcat, (float*)d_out);
    }
}